// Round 8
// baseline (891.809 us; speedup 1.0000x reference)
//
#include <hip/hip_runtime.h>
#include <hip/hip_fp16.h>

#define N_USERS  200000
#define N_ITEMS  100000
#define N_TOPICS 100
#define N_NODES  (N_USERS + N_ITEMS + N_TOPICS)
#define DIM      64
#define BSHIFT   10                               // 1024 rows per bucket
#define BROWS    (1 << BSHIFT)
#define NBUCKETS ((N_NODES + BROWS - 1) >> BSHIFT)   // 294
#define NROWS_PAD (NBUCKETS * BROWS)              // 301,056
#define COLMASK  0x7FFFF                          // 19 bits (N_NODES < 2^19)
#define NB       512                              // binning blocks
#define NBSHIFT  9
#define M_TOT    (NBUCKETS * NB)                  // 150,528 partials
#define SB       256                              // scan blocks
#define CH       ((M_TOT + SB - 1) / SB)
#define S2SPLIT  8                                // scatter2 blocks per bucket
// Padded-CSR: each row padded to a multiple of 8 edges (zero-val entries);
// each bucket owns a fixed region. Bucket padded total ~20650 +- ~140 (28
// sigma below 24576) -> no overflow for this dataset family.
#define BUCKET_CAP 24576

// BSHIFT=10 rationale (confirmed r6): scatter1 cursor active set
// 64 blocks/XCD x NBUCKETS lines must fit 4 MB per-XCD L2.

// ---------- prep: bucket hist + row hist (blocks [0,NB)) + concat ----------

__global__ void prep_kernel(const int* __restrict__ rows,
                            int* __restrict__ partial,
                            int* __restrict__ row_cnt, int n_edges,
                            const float* __restrict__ uemb,
                            const float* __restrict__ iemb,
                            const float* __restrict__ temb,
                            ushort* __restrict__ h0) {
    __shared__ int h[NBUCKETS];
    if (blockIdx.x < NB) {
        for (int i = threadIdx.x; i < NBUCKETS; i += blockDim.x) h[i] = 0;
        __syncthreads();
        int stride = NB * blockDim.x;
        for (int e = blockIdx.x * blockDim.x + threadIdx.x; e < n_edges; e += stride) {
            int r = rows[e];
            atomicAdd(&h[((unsigned)r) >> BSHIFT], 1);
            atomicAdd(&row_cnt[r], 1);            // fire-and-forget, memory-side
        }
        __syncthreads();
        for (int i = threadIdx.x; i < NBUCKETS; i += blockDim.x)
            partial[blockIdx.x * NBUCKETS + i] = h[i];
    } else {
        int g = (blockIdx.x - NB) * blockDim.x + threadIdx.x;  // group of 4
        long base = (long)g * 4;
        if (base >= (long)N_NODES * DIM) return;
        const float* src;
        long off;
        if (base < (long)N_USERS * DIM)                 { src = uemb; off = base; }
        else if (base < (long)(N_USERS + N_ITEMS) * DIM){ src = iemb; off = base - (long)N_USERS * DIM; }
        else                                            { src = temb; off = base - (long)(N_USERS + N_ITEMS) * DIM; }
        float4 v = *(const float4*)(src + off);
        __half2 a = __floats2half2_rn(v.x, v.y);
        __half2 b = __floats2half2_rn(v.z, v.w);
        uint2 o;
        o.x = *(unsigned*)&a;
        o.y = *(unsigned*)&b;
        ((uint2*)h0)[g] = o;
    }
}

// Logical L = bucket*NB + block; physical = block*NBUCKETS + bucket.
__device__ __forceinline__ int phys_idx(int L) {
    return (L & (NB - 1)) * NBUCKETS + (L >> NBSHIFT);
}

__global__ void scanB1_kernel(const int* __restrict__ partial,
                              int* __restrict__ psum) {
    __shared__ int s[256];
    int tid = threadIdx.x;
    int c0 = blockIdx.x * CH;
    int c1 = min(M_TOT, c0 + CH);
    int sum = 0;
    for (int L = c0 + tid; L < c1; L += 256) sum += partial[phys_idx(L)];
    s[tid] = sum;
    __syncthreads();
    for (int off = 128; off > 0; off >>= 1) {
        if (tid < off) s[tid] += s[tid + off];
        __syncthreads();
    }
    if (tid == 0) psum[blockIdx.x] = s[0];
}

// scanB2 folded in: each block reduces psum[0..bid) itself (256 ints, cheap).
__global__ void scanB3_kernel(const int* __restrict__ partial,
                              const int* __restrict__ psum,
                              int* __restrict__ offs) {
    __shared__ int s[SB];
    __shared__ int tile[256];
    __shared__ int carry;
    int tid = threadIdx.x;
    s[tid] = (tid < blockIdx.x) ? psum[tid] : 0;
    __syncthreads();
    for (int off = 128; off > 0; off >>= 1) {
        if (tid < off) s[tid] += s[tid + off];
        __syncthreads();
    }
    if (tid == 0) carry = s[0];
    __syncthreads();
    int c0 = blockIdx.x * CH;
    int c1 = min(M_TOT, c0 + CH);
    for (int base = c0; base < c1; base += 256) {
        int L = base + tid;
        int v = (L < c1) ? partial[phys_idx(L)] : 0;
        tile[tid] = v;
        __syncthreads();
        for (int off = 1; off < 256; off <<= 1) {
            int t = (tid >= off) ? tile[tid - off] : 0;
            __syncthreads();
            tile[tid] += t;
            __syncthreads();
        }
        if (L < c1) offs[L] = carry + tile[tid] - v;
        __syncthreads();
        if (tid == 255) carry += tile[255];
        __syncthreads();
    }
}

__device__ __forceinline__ int pad8(int x) { return (x + 7) & ~7; }

// One 512-thread block per bucket: pad8-scan the 1024 row counts (bucket
// base is FIXED at b*BUCKET_CAP -> buckets independent), emit row_span and
// row_next (atomic cursors for scatter2), zero-fill the pad slots.
__global__ void scanR_kernel(const int* __restrict__ row_cnt,
                             int2* __restrict__ row_span,
                             int* __restrict__ row_next,
                             int2* __restrict__ csr_cv) {
    __shared__ int lcnt[BROWS];
    __shared__ int s[512];
    int b = blockIdx.x;
    int t = threadIdx.x;
    int rbase = b << BSHIFT;
    lcnt[t]       = row_cnt[rbase + t];
    lcnt[t + 512] = row_cnt[rbase + t + 512];
    __syncthreads();
    s[t] = pad8(lcnt[2 * t]) + pad8(lcnt[2 * t + 1]);
    __syncthreads();
    for (int off = 1; off < 512; off <<= 1) {
        int v = (t >= off) ? s[t - off] : 0;
        __syncthreads();
        s[t] += v;                       // inclusive over pairs
        __syncthreads();
    }
    int base = b * BUCKET_CAP + (t ? s[t - 1] : 0);
    int c0 = lcnt[2 * t];
    int c1 = lcnt[2 * t + 1];
    int pe = pad8(c0);
    int po = pad8(c1);
    int p_even = base;
    int p_odd  = base + pe;
    int2 sp0; sp0.x = p_even; sp0.y = p_even + pe;
    int2 sp1; sp1.x = p_odd;  sp1.y = p_odd + po;
    row_span[rbase + 2 * t]     = sp0;
    row_span[rbase + 2 * t + 1] = sp1;
    row_next[rbase + 2 * t]     = p_even;
    row_next[rbase + 2 * t + 1] = p_odd;
    int2 z; z.x = 0; z.y = 0;
    for (int k = c0; k < pe; ++k) csr_cv[p_even + k] = z;
    for (int k = c1; k < po; ++k) csr_cv[p_odd + k]  = z;
}

// Bin edges into 1024-row buckets at exact positions; LDS-only atomics.
// 512 threads/block, grid fixed at NB (mapping must match prep hist part).
__global__ void scatter1_kernel(const int* __restrict__ rows,
                                const int* __restrict__ cols,
                                const float* __restrict__ vals,
                                const int* __restrict__ offs,
                                int2* __restrict__ bkt_buf, int n_edges) {
    __shared__ int lpos[NBUCKETS];
    for (int i = threadIdx.x; i < NBUCKETS; i += blockDim.x)
        lpos[i] = offs[i * NB + blockIdx.x];
    __syncthreads();
    int stride = gridDim.x * blockDim.x;
    for (int e = blockIdx.x * blockDim.x + threadIdx.x; e < n_edges; e += stride) {
        int r = rows[e];
        int b = ((unsigned)r) >> BSHIFT;
        int pos = atomicAdd(&lpos[b], 1);
        int2 p;
        p.x = cols[e] | ((r & (BROWS - 1)) << 19);   // 19+10 bits < 32
        p.y = __float_as_int(vals[e]);
        bkt_buf[pos] = p;
    }
}

// Pure placement pass: S2SPLIT blocks per bucket (vs 1 at r7: 9 -> ~36
// waves/CU), single read of bkt_buf, slot claim via global atomic cursor
// (row_next is 1.2 MB, L2-hot; csr writes stay in the bucket's 196 KB
// window -> no round-4 write amplification).
__global__ void scatter2_kernel(const int2* __restrict__ bkt_buf,
                                const int* __restrict__ offs,
                                int* __restrict__ row_next,
                                int2* __restrict__ csr_cv, int n_edges) {
    int b = blockIdx.x / S2SPLIT;
    int c = blockIdx.x % S2SPLIT;
    int e0 = offs[b * NB];
    int e1 = (b == NBUCKETS - 1) ? n_edges : offs[(b + 1) * NB];
    int rbase = b << BSHIFT;
    for (int e = e0 + c * blockDim.x + threadIdx.x; e < e1;
         e += S2SPLIT * blockDim.x) {
        int2 p = bkt_buf[e];
        int row = rbase + (((unsigned)p.x) >> 19);
        int pos = atomicAdd(&row_next[row], 1);
        int2 cv;
        cv.x = p.x & COLMASK;
        cv.y = p.y;
        csr_cv[pos] = cv;
    }
}

// ---------- SpMV helpers ----------
// fmaf(half2float(h), w, acc) lowers to v_fma_mix_f32 (fp16 src, fp32 MAC).
__device__ __forceinline__ float4 fma_mix4(const ushort* __restrict__ h,
                                           int row, int l16, float w,
                                           float4 acc) {
    uint2 r = ((const uint2*)(h + (size_t)row * DIM))[l16];
    __half2 h01 = *(__half2*)&r.x;
    __half2 h23 = *(__half2*)&r.y;
    acc.x = __builtin_fmaf(__half2float(__low2half(h01)),  w, acc.x);
    acc.y = __builtin_fmaf(__half2float(__high2half(h01)), w, acc.y);
    acc.z = __builtin_fmaf(__half2float(__low2half(h23)),  w, acc.z);
    acc.w = __builtin_fmaf(__half2float(__high2half(h23)), w, acc.w);
    return acc;
}

// Process one 8-edge batch: 4 unconditional int4 loads (rows are padded to
// a multiple of 8 with zero-val entries -> no clamps, no ternaries).
__device__ __forceinline__ float4 batch8(const int2* __restrict__ csr_cv,
                                         const ushort* __restrict__ h_src,
                                         int p, int l16, float4 acc) {
    const int4* q = (const int4*)(csr_cv + p);
    int4 a = q[0], b = q[1], c = q[2], d = q[3];
    acc = fma_mix4(h_src, a.x, l16, __int_as_float(a.y), acc);
    acc = fma_mix4(h_src, a.z, l16, __int_as_float(a.w), acc);
    acc = fma_mix4(h_src, b.x, l16, __int_as_float(b.y), acc);
    acc = fma_mix4(h_src, b.z, l16, __int_as_float(b.w), acc);
    acc = fma_mix4(h_src, c.x, l16, __int_as_float(c.y), acc);
    acc = fma_mix4(h_src, c.z, l16, __int_as_float(c.w), acc);
    acc = fma_mix4(h_src, d.x, l16, __int_as_float(d.y), acc);
    acc = fma_mix4(h_src, d.z, l16, __int_as_float(d.w), acc);
    return acc;
}

#define NWAVES ((N_NODES + 3) / 4)    // spmv waves; tail waves do the gather

// Full-table SpMV: 4 rows/wave (1 per 16-lane group), 8 edges in flight.
// (8-unroll is the proven optimum.) Tail waves perform the fused batch-row
// gather of h_src (u_acc/it_acc init or add).
__global__ void spmv_csr_kernel(const int2* __restrict__ row_span,
                                const int2* __restrict__ csr_cv,
                                const ushort* __restrict__ h_src,
                                ushort* __restrict__ h_dst,
                                const int* __restrict__ users,
                                const int* __restrict__ items,
                                float* __restrict__ u_acc,
                                float* __restrict__ it_acc,
                                int B, int first) {
    int wave = (int)(((long)blockIdx.x * blockDim.x + threadIdx.x) >> 6);
    int lane = threadIdx.x & 63;
    int g    = lane >> 4;
    int l16  = lane & 15;
    if (wave < NWAVES) {
        int r    = wave * 4 + g;
        int rc   = min(r, N_NODES - 1);
        int2 sp  = row_span[rc];
        int p0   = sp.x;
        int len  = (r < N_NODES) ? (sp.y - sp.x) : 0;   // multiple of 8
        int m = max(len, __shfl_xor(len, 16, 64));
        m = max(m, __shfl_xor(m, 32, 64));
        float4 acc = make_float4(0.f, 0.f, 0.f, 0.f);
        for (int off = 0; off < m; off += 8) {
            if (off < len)
                acc = batch8(csr_cv, h_src, p0 + off, l16, acc);
        }
        if (r < N_NODES) {
            __half2 a = __floats2half2_rn(acc.x, acc.y);
            __half2 b = __floats2half2_rn(acc.z, acc.w);
            uint2 o;
            o.x = *(unsigned*)&a;
            o.y = *(unsigned*)&b;
            ((uint2*)(h_dst + (size_t)r * DIM))[l16] = o;
        }
    } else {
        int s = (wave - NWAVES) * 4 + g;
        if (s >= 2 * B) return;
        int node = (s < B) ? users[s] : (N_USERS + items[s - B]);
        uint2 hr = ((const uint2*)(h_src + (size_t)node * DIM))[l16];
        float2 a01 = __half22float2(*(__half2*)&hr.x);
        float2 a23 = __half22float2(*(__half2*)&hr.y);
        float* dst = (s < B) ? (u_acc + (size_t)s * DIM)
                             : (it_acc + (size_t)(s - B) * DIM);
        float4* p = (float4*)dst + l16;
        if (first) {
            *p = make_float4(a01.x, a01.y, a23.x, a23.y);
        } else {
            float4 o = *p;
            o.x += a01.x; o.y += a01.y; o.z += a23.x; o.w += a23.y;
            *p = o;
        }
    }
}

// Layer-3 SpMV over BATCH ROWS ONLY; acc initialized with the h2 fragment
// (fuses the final gather_add).
__global__ void spmv_batch_kernel(const int2* __restrict__ row_span,
                                  const int2* __restrict__ csr_cv,
                                  const ushort* __restrict__ h_src,
                                  const int* __restrict__ users,
                                  const int* __restrict__ items,
                                  float* __restrict__ u_acc,
                                  float* __restrict__ it_acc, int B) {
    int wave = (int)(((long)blockIdx.x * blockDim.x + threadIdx.x) >> 6);
    int lane = threadIdx.x & 63;
    int g    = lane >> 4;
    int l16  = lane & 15;
    int s    = wave * 4 + g;
    bool ok  = s < 2 * B;
    int node = 0;
    if (ok) node = (s < B) ? users[s] : (N_USERS + items[s - B]);
    float4 acc = make_float4(0.f, 0.f, 0.f, 0.f);
    if (ok) {
        uint2 hr = ((const uint2*)(h_src + (size_t)node * DIM))[l16];
        float2 a01 = __half22float2(*(__half2*)&hr.x);
        float2 a23 = __half22float2(*(__half2*)&hr.y);
        acc = make_float4(a01.x, a01.y, a23.x, a23.y);
    }
    int2 sp  = row_span[node];
    int p0   = sp.x;
    int len  = ok ? (sp.y - sp.x) : 0;
    int m = max(len, __shfl_xor(len, 16, 64));
    m = max(m, __shfl_xor(m, 32, 64));
    for (int off = 0; off < m; off += 8) {
        if (off < len)
            acc = batch8(csr_cv, h_src, p0 + off, l16, acc);
    }
    if (ok) {
        float* dst = (s < B) ? (u_acc + (size_t)s * DIM)
                             : (it_acc + (size_t)(s - B) * DIM);
        float4* p = (float4*)dst + l16;
        float4 old = *p;
        old.x += acc.x; old.y += acc.y; old.z += acc.z; old.w += acc.w;
        *p = old;
    }
}

__global__ void dot_kernel(const float* __restrict__ u_acc,
                           const float* __restrict__ it_acc,
                           float* __restrict__ out, int B) {
    int gid  = blockIdx.x * blockDim.x + threadIdx.x;
    int b    = gid >> 6;
    int lane = gid & 63;
    if (b >= B) return;
    float p = u_acc[(size_t)b * DIM + lane] * it_acc[(size_t)b * DIM + lane];
    #pragma unroll
    for (int off = 32; off > 0; off >>= 1)
        p += __shfl_down(p, off, 64);
    if (lane == 0) out[b] = p * (1.0f / 16.0f);
}

extern "C" void kernel_launch(void* const* d_in, const int* in_sizes, int n_in,
                              void* d_out, int out_size, void* d_ws, size_t ws_size,
                              hipStream_t stream) {
    const int*   users = (const int*)d_in[0];
    const int*   items = (const int*)d_in[1];
    const int*   erows = (const int*)d_in[2];
    const int*   ecols = (const int*)d_in[3];
    const float* evals = (const float*)d_in[4];
    const float* uemb  = (const float*)d_in[5];
    const float* iemb  = (const float*)d_in[6];
    const float* temb  = (const float*)d_in[7];
    float* out = (float*)d_out;

    const int n_edges = in_sizes[2];
    const int B       = in_sizes[0];

    const size_t h2bytes = (((size_t)N_NODES * DIM * 2 + 255) / 256) * 256;  // 38.4 MB
    const size_t abytes  = (size_t)B * DIM * sizeof(float);                  // 4.2 MB
    const size_t spbytes = (((size_t)NROWS_PAD * 8 + 255) / 256) * 256;      // 2.4 MB
    const size_t csrbytes= (size_t)NBUCKETS * BUCKET_CAP * 8;                // 57.8 MB
    const size_t bkbytes = (size_t)n_edges * 8;                              // 40 MB
    const size_t mbytes  = (((size_t)M_TOT * 4 + 255) / 256) * 256;          // 0.6 MB
    const size_t cbytes  = (((size_t)NROWS_PAD * 4 + 255) / 256) * 256;      // 1.2 MB

    char* ws = (char*)d_ws;
    size_t off = 0;
    ushort* hA       = (ushort*)(ws + off); off += h2bytes;
    ushort* hB       = (ushort*)(ws + off); off += h2bytes;
    float*  u_acc    = (float*) (ws + off); off += abytes;
    float*  it_acc   = (float*) (ws + off); off += abytes;
    int2*   row_span = (int2*)  (ws + off); off += spbytes;
    int2*   csr_cv   = (int2*)  (ws + off); off += csrbytes;
    int2*   bkt_buf  = (int2*)  (ws + off); off += bkbytes;
    int*    partial  = (int*)   (ws + off); off += mbytes;
    int*    offs     = (int*)   (ws + off); off += mbytes;
    int*    row_cnt  = (int*)   (ws + off); off += cbytes;
    int*    row_next = (int*)   (ws + off); off += cbytes;
    int*    psum     = (int*)   (ws + off); off += 4096;   // ~190 MB total

    dim3 blk(256);
    dim3 blk512(512);

    // ---- CSR build + h0 concat fused into hist pass ----
    hipMemsetAsync(row_cnt, 0, (size_t)NROWS_PAD * 4, stream);
    const long n4 = (long)N_NODES * DIM / 4;
    const int  nconcat = (int)((n4 + 511) / 512);
    prep_kernel<<<NB + nconcat, blk512, 0, stream>>>(erows, partial, row_cnt,
                                                     n_edges, uemb, iemb, temb, hA);
    scanB1_kernel<<<SB, blk, 0, stream>>>(partial, psum);
    scanB3_kernel<<<SB, blk, 0, stream>>>(partial, psum, offs);
    scanR_kernel<<<NBUCKETS, blk512, 0, stream>>>(row_cnt, row_span, row_next, csr_cv);
    scatter1_kernel<<<NB, blk512, 0, stream>>>(erows, ecols, evals, offs, bkt_buf, n_edges);
    scatter2_kernel<<<NBUCKETS * S2SPLIT, blk, 0, stream>>>(bkt_buf, offs,
                                                            row_next, csr_cv, n_edges);

    // ---- layers 1,2: full-table SpMV (+fused batch gather of h_src);
    //      layer 3: batch rows only (+fused h2 gather via acc init) ----
    const int gwaves  = (2 * B + 3) / 4;
    const int fblocks = (int)(((long)(NWAVES + gwaves) * 64 + 255) / 256);
    spmv_csr_kernel<<<fblocks, blk, 0, stream>>>(row_span, csr_cv, hA, hB,
                                                 users, items, u_acc, it_acc, B, 1);
    spmv_csr_kernel<<<fblocks, blk, 0, stream>>>(row_span, csr_cv, hB, hA,
                                                 users, items, u_acc, it_acc, B, 0);
    const int bblocks = (int)(((long)gwaves * 64 + 255) / 256);
    spmv_batch_kernel<<<bblocks, blk, 0, stream>>>(row_span, csr_cv, hA,
                                                   users, items, u_acc, it_acc, B);

    dot_kernel<<<(B * 64 + 255) / 256, blk, 0, stream>>>(u_acc, it_acc, out, B);
}

// Round 9
// 699.107 us; speedup vs baseline: 1.2756x; 1.2756x over previous
//
#include <hip/hip_runtime.h>
#include <hip/hip_fp16.h>

#define N_USERS  200000
#define N_ITEMS  100000
#define N_TOPICS 100
#define N_NODES  (N_USERS + N_ITEMS + N_TOPICS)
#define DIM      64
#define BSHIFT   10                               // 1024 rows per bucket
#define BROWS    (1 << BSHIFT)
#define NBUCKETS ((N_NODES + BROWS - 1) >> BSHIFT)   // 294
#define NROWS_PAD (NBUCKETS * BROWS)              // 301,056
#define COLMASK  0x7FFFF                          // 19 bits (N_NODES < 2^19)
#define NB       512                              // binning blocks
#define NBSHIFT  9
#define M_TOT    (NBUCKETS * NB)                  // 150,528 partials
#define SB       256                              // scan blocks
#define CH       ((M_TOT + SB - 1) / SB)
// Padded-CSR: each row padded to a multiple of 8 edges (zero-val entries);
// each bucket owns a fixed region. Bucket padded total ~20650 +- ~140 (28
// sigma below 24576) -> no overflow for this dataset family.
#define BUCKET_CAP 24576

// Hard-won write-amplification rules (r4/r5/r8):
//  - scattered sub-line global stores are ~5-8x amplified unless the
//    destination's active-line set fits per-XCD L2 AND each destination
//    window is written by ONE block (one XCD). S2SPLIT=8 bucket-sharing
//    cost 275 MB writes for 48 MB payload (r8).
//  - BSHIFT=10: scatter1 cursor active set 64 blocks/XCD x NBUCKETS lines
//    must fit 4 MB per-XCD L2 (confirmed r6).

// ---------- prep: bucket hist + row hist (blocks [0,NB)) + concat ----------

__global__ void prep_kernel(const int* __restrict__ rows,
                            int* __restrict__ partial,
                            int* __restrict__ row_cnt, int n_edges,
                            const float* __restrict__ uemb,
                            const float* __restrict__ iemb,
                            const float* __restrict__ temb,
                            ushort* __restrict__ h0) {
    __shared__ int h[NBUCKETS];
    if (blockIdx.x < NB) {
        for (int i = threadIdx.x; i < NBUCKETS; i += blockDim.x) h[i] = 0;
        __syncthreads();
        int stride = NB * blockDim.x;
        for (int e = blockIdx.x * blockDim.x + threadIdx.x; e < n_edges; e += stride) {
            int r = rows[e];
            atomicAdd(&h[((unsigned)r) >> BSHIFT], 1);
            atomicAdd(&row_cnt[r], 1);            // fire-and-forget, memory-side
        }
        __syncthreads();
        for (int i = threadIdx.x; i < NBUCKETS; i += blockDim.x)
            partial[blockIdx.x * NBUCKETS + i] = h[i];
    } else {
        int g = (blockIdx.x - NB) * blockDim.x + threadIdx.x;  // group of 4
        long base = (long)g * 4;
        if (base >= (long)N_NODES * DIM) return;
        const float* src;
        long off;
        if (base < (long)N_USERS * DIM)                 { src = uemb; off = base; }
        else if (base < (long)(N_USERS + N_ITEMS) * DIM){ src = iemb; off = base - (long)N_USERS * DIM; }
        else                                            { src = temb; off = base - (long)(N_USERS + N_ITEMS) * DIM; }
        float4 v = *(const float4*)(src + off);
        __half2 a = __floats2half2_rn(v.x, v.y);
        __half2 b = __floats2half2_rn(v.z, v.w);
        uint2 o;
        o.x = *(unsigned*)&a;
        o.y = *(unsigned*)&b;
        ((uint2*)h0)[g] = o;
    }
}

// Logical L = bucket*NB + block; physical = block*NBUCKETS + bucket.
__device__ __forceinline__ int phys_idx(int L) {
    return (L & (NB - 1)) * NBUCKETS + (L >> NBSHIFT);
}

__global__ void scanB1_kernel(const int* __restrict__ partial,
                              int* __restrict__ psum) {
    __shared__ int s[256];
    int tid = threadIdx.x;
    int c0 = blockIdx.x * CH;
    int c1 = min(M_TOT, c0 + CH);
    int sum = 0;
    for (int L = c0 + tid; L < c1; L += 256) sum += partial[phys_idx(L)];
    s[tid] = sum;
    __syncthreads();
    for (int off = 128; off > 0; off >>= 1) {
        if (tid < off) s[tid] += s[tid + off];
        __syncthreads();
    }
    if (tid == 0) psum[blockIdx.x] = s[0];
}

// scanB2 folded in: each block reduces psum[0..bid) itself (256 ints, cheap).
__global__ void scanB3_kernel(const int* __restrict__ partial,
                              const int* __restrict__ psum,
                              int* __restrict__ offs) {
    __shared__ int s[SB];
    __shared__ int tile[256];
    __shared__ int carry;
    int tid = threadIdx.x;
    s[tid] = (tid < blockIdx.x) ? psum[tid] : 0;
    __syncthreads();
    for (int off = 128; off > 0; off >>= 1) {
        if (tid < off) s[tid] += s[tid + off];
        __syncthreads();
    }
    if (tid == 0) carry = s[0];
    __syncthreads();
    int c0 = blockIdx.x * CH;
    int c1 = min(M_TOT, c0 + CH);
    for (int base = c0; base < c1; base += 256) {
        int L = base + tid;
        int v = (L < c1) ? partial[phys_idx(L)] : 0;
        tile[tid] = v;
        __syncthreads();
        for (int off = 1; off < 256; off <<= 1) {
            int t = (tid >= off) ? tile[tid - off] : 0;
            __syncthreads();
            tile[tid] += t;
            __syncthreads();
        }
        if (L < c1) offs[L] = carry + tile[tid] - v;
        __syncthreads();
        if (tid == 255) carry += tile[255];
        __syncthreads();
    }
}

__device__ __forceinline__ int pad8(int x) { return (x + 7) & ~7; }

// One 512-thread block per bucket: pad8-scan the 1024 row counts (bucket
// base is FIXED at b*BUCKET_CAP -> buckets independent), emit row_span,
// zero-fill the pad slots.
__global__ void scanR_kernel(const int* __restrict__ row_cnt,
                             int2* __restrict__ row_span,
                             int2* __restrict__ csr_cv) {
    __shared__ int lcnt[BROWS];
    __shared__ int s[512];
    int b = blockIdx.x;
    int t = threadIdx.x;
    int rbase = b << BSHIFT;
    lcnt[t]       = row_cnt[rbase + t];
    lcnt[t + 512] = row_cnt[rbase + t + 512];
    __syncthreads();
    s[t] = pad8(lcnt[2 * t]) + pad8(lcnt[2 * t + 1]);
    __syncthreads();
    for (int off = 1; off < 512; off <<= 1) {
        int v = (t >= off) ? s[t - off] : 0;
        __syncthreads();
        s[t] += v;                       // inclusive over pairs
        __syncthreads();
    }
    int base = b * BUCKET_CAP + (t ? s[t - 1] : 0);
    int c0 = lcnt[2 * t];
    int c1 = lcnt[2 * t + 1];
    int pe = pad8(c0);
    int po = pad8(c1);
    int p_even = base;
    int p_odd  = base + pe;
    int2 sp0; sp0.x = p_even; sp0.y = p_even + pe;
    int2 sp1; sp1.x = p_odd;  sp1.y = p_odd + po;
    row_span[rbase + 2 * t]     = sp0;
    row_span[rbase + 2 * t + 1] = sp1;
    int2 z; z.x = 0; z.y = 0;
    for (int k = c0; k < pe; ++k) csr_cv[p_even + k] = z;
    for (int k = c1; k < po; ++k) csr_cv[p_odd + k]  = z;
}

// Bin edges into 1024-row buckets at exact positions; LDS-only atomics.
// 512 threads/block, grid fixed at NB (mapping must match prep hist part).
__global__ void scatter1_kernel(const int* __restrict__ rows,
                                const int* __restrict__ cols,
                                const float* __restrict__ vals,
                                const int* __restrict__ offs,
                                int2* __restrict__ bkt_buf, int n_edges) {
    __shared__ int lpos[NBUCKETS];
    for (int i = threadIdx.x; i < NBUCKETS; i += blockDim.x)
        lpos[i] = offs[i * NB + blockIdx.x];
    __syncthreads();
    int stride = gridDim.x * blockDim.x;
    for (int e = blockIdx.x * blockDim.x + threadIdx.x; e < n_edges; e += stride) {
        int r = rows[e];
        int b = ((unsigned)r) >> BSHIFT;
        int pos = atomicAdd(&lpos[b], 1);
        int2 p;
        p.x = cols[e] | ((r & (BROWS - 1)) << 19);   // 19+10 bits < 32
        p.y = __float_as_int(vals[e]);
        bkt_buf[pos] = p;
    }
}

// Placement-only pass: ONE 1024-thread block per bucket (single-XCD writes
// per 196 KB window -> no r8 cross-XCD line bouncing), LDS row cursors
// seeded from row_span (no hist pass: bkt_buf is read exactly ONCE).
__global__ void scatter2_kernel(const int2* __restrict__ bkt_buf,
                                const int* __restrict__ offs,
                                const int2* __restrict__ row_span,
                                int2* __restrict__ csr_cv, int n_edges) {
    __shared__ int lptr[BROWS];
    __shared__ int lfill[BROWS];
    int b = blockIdx.x;
    int t = threadIdx.x;
    int rbase = b << BSHIFT;
    lptr[t]  = row_span[rbase + t].x;
    lfill[t] = 0;
    __syncthreads();
    int e0 = offs[b * NB];
    int e1 = (b == NBUCKETS - 1) ? n_edges : offs[(b + 1) * NB];
    for (int e = e0 + t; e < e1; e += blockDim.x) {
        int2 p = bkt_buf[e];
        int delta = ((unsigned)p.x) >> 19;
        int pos = lptr[delta] + atomicAdd(&lfill[delta], 1);
        int2 cv;
        cv.x = p.x & COLMASK;
        cv.y = p.y;
        csr_cv[pos] = cv;
    }
}

// ---------- SpMV helpers ----------
// fmaf(half2float(h), w, acc) lowers to v_fma_mix_f32 (fp16 src, fp32 MAC).
__device__ __forceinline__ float4 fma_mix4(const ushort* __restrict__ h,
                                           int row, int l16, float w,
                                           float4 acc) {
    uint2 r = ((const uint2*)(h + (size_t)row * DIM))[l16];
    __half2 h01 = *(__half2*)&r.x;
    __half2 h23 = *(__half2*)&r.y;
    acc.x = __builtin_fmaf(__half2float(__low2half(h01)),  w, acc.x);
    acc.y = __builtin_fmaf(__half2float(__high2half(h01)), w, acc.y);
    acc.z = __builtin_fmaf(__half2float(__low2half(h23)),  w, acc.z);
    acc.w = __builtin_fmaf(__half2float(__high2half(h23)), w, acc.w);
    return acc;
}

// Process one 8-edge batch: 4 unconditional int4 loads (rows are padded to
// a multiple of 8 with zero-val entries -> no clamps, no ternaries).
__device__ __forceinline__ float4 batch8(const int2* __restrict__ csr_cv,
                                         const ushort* __restrict__ h_src,
                                         int p, int l16, float4 acc) {
    const int4* q = (const int4*)(csr_cv + p);
    int4 a = q[0], b = q[1], c = q[2], d = q[3];
    acc = fma_mix4(h_src, a.x, l16, __int_as_float(a.y), acc);
    acc = fma_mix4(h_src, a.z, l16, __int_as_float(a.w), acc);
    acc = fma_mix4(h_src, b.x, l16, __int_as_float(b.y), acc);
    acc = fma_mix4(h_src, b.z, l16, __int_as_float(b.w), acc);
    acc = fma_mix4(h_src, c.x, l16, __int_as_float(c.y), acc);
    acc = fma_mix4(h_src, c.z, l16, __int_as_float(c.w), acc);
    acc = fma_mix4(h_src, d.x, l16, __int_as_float(d.y), acc);
    acc = fma_mix4(h_src, d.z, l16, __int_as_float(d.w), acc);
    return acc;
}

#define NWAVES ((N_NODES + 3) / 4)    // spmv waves; tail waves do the gather

// Full-table SpMV: 4 rows/wave (1 per 16-lane group), 8 edges in flight.
// (8-unroll is the proven optimum.) Tail waves perform the fused batch-row
// gather of h_src (u_acc/it_acc init or add).
__global__ void spmv_csr_kernel(const int2* __restrict__ row_span,
                                const int2* __restrict__ csr_cv,
                                const ushort* __restrict__ h_src,
                                ushort* __restrict__ h_dst,
                                const int* __restrict__ users,
                                const int* __restrict__ items,
                                float* __restrict__ u_acc,
                                float* __restrict__ it_acc,
                                int B, int first) {
    int wave = (int)(((long)blockIdx.x * blockDim.x + threadIdx.x) >> 6);
    int lane = threadIdx.x & 63;
    int g    = lane >> 4;
    int l16  = lane & 15;
    if (wave < NWAVES) {
        int r    = wave * 4 + g;
        int rc   = min(r, N_NODES - 1);
        int2 sp  = row_span[rc];
        int p0   = sp.x;
        int len  = (r < N_NODES) ? (sp.y - sp.x) : 0;   // multiple of 8
        int m = max(len, __shfl_xor(len, 16, 64));
        m = max(m, __shfl_xor(m, 32, 64));
        float4 acc = make_float4(0.f, 0.f, 0.f, 0.f);
        for (int off = 0; off < m; off += 8) {
            if (off < len)
                acc = batch8(csr_cv, h_src, p0 + off, l16, acc);
        }
        if (r < N_NODES) {
            __half2 a = __floats2half2_rn(acc.x, acc.y);
            __half2 b = __floats2half2_rn(acc.z, acc.w);
            uint2 o;
            o.x = *(unsigned*)&a;
            o.y = *(unsigned*)&b;
            ((uint2*)(h_dst + (size_t)r * DIM))[l16] = o;
        }
    } else {
        int s = (wave - NWAVES) * 4 + g;
        if (s >= 2 * B) return;
        int node = (s < B) ? users[s] : (N_USERS + items[s - B]);
        uint2 hr = ((const uint2*)(h_src + (size_t)node * DIM))[l16];
        float2 a01 = __half22float2(*(__half2*)&hr.x);
        float2 a23 = __half22float2(*(__half2*)&hr.y);
        float* dst = (s < B) ? (u_acc + (size_t)s * DIM)
                             : (it_acc + (size_t)(s - B) * DIM);
        float4* p = (float4*)dst + l16;
        if (first) {
            *p = make_float4(a01.x, a01.y, a23.x, a23.y);
        } else {
            float4 o = *p;
            o.x += a01.x; o.y += a01.y; o.z += a23.x; o.w += a23.y;
            *p = o;
        }
    }
}

// Layer-3 SpMV over BATCH ROWS ONLY; acc initialized with the h2 fragment
// (fuses the final gather_add).
__global__ void spmv_batch_kernel(const int2* __restrict__ row_span,
                                  const int2* __restrict__ csr_cv,
                                  const ushort* __restrict__ h_src,
                                  const int* __restrict__ users,
                                  const int* __restrict__ items,
                                  float* __restrict__ u_acc,
                                  float* __restrict__ it_acc, int B) {
    int wave = (int)(((long)blockIdx.x * blockDim.x + threadIdx.x) >> 6);
    int lane = threadIdx.x & 63;
    int g    = lane >> 4;
    int l16  = lane & 15;
    int s    = wave * 4 + g;
    bool ok  = s < 2 * B;
    int node = 0;
    if (ok) node = (s < B) ? users[s] : (N_USERS + items[s - B]);
    float4 acc = make_float4(0.f, 0.f, 0.f, 0.f);
    if (ok) {
        uint2 hr = ((const uint2*)(h_src + (size_t)node * DIM))[l16];
        float2 a01 = __half22float2(*(__half2*)&hr.x);
        float2 a23 = __half22float2(*(__half2*)&hr.y);
        acc = make_float4(a01.x, a01.y, a23.x, a23.y);
    }
    int2 sp  = row_span[node];
    int p0   = sp.x;
    int len  = ok ? (sp.y - sp.x) : 0;
    int m = max(len, __shfl_xor(len, 16, 64));
    m = max(m, __shfl_xor(m, 32, 64));
    for (int off = 0; off < m; off += 8) {
        if (off < len)
            acc = batch8(csr_cv, h_src, p0 + off, l16, acc);
    }
    if (ok) {
        float* dst = (s < B) ? (u_acc + (size_t)s * DIM)
                             : (it_acc + (size_t)(s - B) * DIM);
        float4* p = (float4*)dst + l16;
        float4 old = *p;
        old.x += acc.x; old.y += acc.y; old.z += acc.z; old.w += acc.w;
        *p = old;
    }
}

__global__ void dot_kernel(const float* __restrict__ u_acc,
                           const float* __restrict__ it_acc,
                           float* __restrict__ out, int B) {
    int gid  = blockIdx.x * blockDim.x + threadIdx.x;
    int b    = gid >> 6;
    int lane = gid & 63;
    if (b >= B) return;
    float p = u_acc[(size_t)b * DIM + lane] * it_acc[(size_t)b * DIM + lane];
    #pragma unroll
    for (int off = 32; off > 0; off >>= 1)
        p += __shfl_down(p, off, 64);
    if (lane == 0) out[b] = p * (1.0f / 16.0f);
}

extern "C" void kernel_launch(void* const* d_in, const int* in_sizes, int n_in,
                              void* d_out, int out_size, void* d_ws, size_t ws_size,
                              hipStream_t stream) {
    const int*   users = (const int*)d_in[0];
    const int*   items = (const int*)d_in[1];
    const int*   erows = (const int*)d_in[2];
    const int*   ecols = (const int*)d_in[3];
    const float* evals = (const float*)d_in[4];
    const float* uemb  = (const float*)d_in[5];
    const float* iemb  = (const float*)d_in[6];
    const float* temb  = (const float*)d_in[7];
    float* out = (float*)d_out;

    const int n_edges = in_sizes[2];
    const int B       = in_sizes[0];

    const size_t h2bytes = (((size_t)N_NODES * DIM * 2 + 255) / 256) * 256;  // 38.4 MB
    const size_t abytes  = (size_t)B * DIM * sizeof(float);                  // 4.2 MB
    const size_t spbytes = (((size_t)NROWS_PAD * 8 + 255) / 256) * 256;      // 2.4 MB
    const size_t csrbytes= (size_t)NBUCKETS * BUCKET_CAP * 8;                // 57.8 MB
    const size_t bkbytes = (size_t)n_edges * 8;                              // 40 MB
    const size_t mbytes  = (((size_t)M_TOT * 4 + 255) / 256) * 256;          // 0.6 MB
    const size_t cbytes  = (((size_t)NROWS_PAD * 4 + 255) / 256) * 256;      // 1.2 MB

    char* ws = (char*)d_ws;
    size_t off = 0;
    ushort* hA       = (ushort*)(ws + off); off += h2bytes;
    ushort* hB       = (ushort*)(ws + off); off += h2bytes;
    float*  u_acc    = (float*) (ws + off); off += abytes;
    float*  it_acc   = (float*) (ws + off); off += abytes;
    int2*   row_span = (int2*)  (ws + off); off += spbytes;
    int2*   csr_cv   = (int2*)  (ws + off); off += csrbytes;
    int2*   bkt_buf  = (int2*)  (ws + off); off += bkbytes;
    int*    partial  = (int*)   (ws + off); off += mbytes;
    int*    offs     = (int*)   (ws + off); off += mbytes;
    int*    row_cnt  = (int*)   (ws + off); off += cbytes;
    int*    psum     = (int*)   (ws + off); off += 4096;   // ~189 MB total

    dim3 blk(256);
    dim3 blk512(512);
    dim3 blk1k(1024);

    // ---- CSR build + h0 concat fused into hist pass ----
    hipMemsetAsync(row_cnt, 0, (size_t)NROWS_PAD * 4, stream);
    const long n4 = (long)N_NODES * DIM / 4;
    const int  nconcat = (int)((n4 + 511) / 512);
    prep_kernel<<<NB + nconcat, blk512, 0, stream>>>(erows, partial, row_cnt,
                                                     n_edges, uemb, iemb, temb, hA);
    scanB1_kernel<<<SB, blk, 0, stream>>>(partial, psum);
    scanB3_kernel<<<SB, blk, 0, stream>>>(partial, psum, offs);
    scanR_kernel<<<NBUCKETS, blk512, 0, stream>>>(row_cnt, row_span, csr_cv);
    scatter1_kernel<<<NB, blk512, 0, stream>>>(erows, ecols, evals, offs, bkt_buf, n_edges);
    scatter2_kernel<<<NBUCKETS, blk1k, 0, stream>>>(bkt_buf, offs, row_span,
                                                    csr_cv, n_edges);

    // ---- layers 1,2: full-table SpMV (+fused batch gather of h_src);
    //      layer 3: batch rows only (+fused h2 gather via acc init) ----
    const int gwaves  = (2 * B + 3) / 4;
    const int fblocks = (int)(((long)(NWAVES + gwaves) * 64 + 255) / 256);
    spmv_csr_kernel<<<fblocks, blk, 0, stream>>>(row_span, csr_cv, hA, hB,
                                                 users, items, u_acc, it_acc, B, 1);
    spmv_csr_kernel<<<fblocks, blk, 0, stream>>>(row_span, csr_cv, hB, hA,
                                                 users, items, u_acc, it_acc, B, 0);
    const int bblocks = (int)(((long)gwaves * 64 + 255) / 256);
    spmv_batch_kernel<<<bblocks, blk, 0, stream>>>(row_span, csr_cv, hA,
                                                   users, items, u_acc, it_acc, B);

    dot_kernel<<<(B * 64 + 255) / 256, blk, 0, stream>>>(u_acc, it_acc, out, B);
}

// Round 10
// 696.192 us; speedup vs baseline: 1.2810x; 1.0042x over previous
//
#include <hip/hip_runtime.h>
#include <hip/hip_fp16.h>

#define N_USERS  200000
#define N_ITEMS  100000
#define N_TOPICS 100
#define N_NODES  (N_USERS + N_ITEMS + N_TOPICS)
#define DIM      64
#define BSHIFT   10                               // 1024 rows per bucket
#define BROWS    (1 << BSHIFT)
#define NBUCKETS ((N_NODES + BROWS - 1) >> BSHIFT)   // 294
#define NROWS_PAD (NBUCKETS * BROWS)              // 301,056
#define COLMASK  0x7FFFF                          // 19 bits (N_NODES < 2^19)
#define NB       512                              // binning blocks
#define NBSHIFT  9
#define M_TOT    (NBUCKETS * NB)                  // 150,528 partials
#define SB       256                              // scan blocks
#define CH       ((M_TOT + SB - 1) / SB)
#define NHCOPY   8                                // privatized row-hist copies
// Padded-CSR: each row padded to a multiple of 8 edges (zero-val entries);
// each bucket owns a fixed region. Bucket padded total ~20650 +- ~140 (28
// sigma below 24576) -> no overflow for this dataset family.
#define BUCKET_CAP 24576

// Cross-XCD line-sharing rule (r4/r8/r9 unified): any sub-line store/RMW
// pattern where the same 128B lines are touched from multiple XCDs bounces
// between non-coherent L2s -> 5-8x HBM write amplification. Fixes used here:
//  - scatter1 cursors: NBUCKETS small enough that active lines fit L2 (r6).
//  - scatter2: ONE block owns each bucket's csr window (r8 lesson).
//  - row hist: NHCOPY=8 privatized copies, copy = blockIdx&7 ~ XCD (r9
//    lesson: a single shared 1.2MB hist cost 150 MB of write bounce).

// ---------- prep: bucket hist + private row hist + concat ----------

__global__ void prep_kernel(const int* __restrict__ rows,
                            int* __restrict__ partial,
                            int* __restrict__ row_cnt8, int n_edges,
                            const float* __restrict__ uemb,
                            const float* __restrict__ iemb,
                            const float* __restrict__ temb,
                            ushort* __restrict__ h0) {
    __shared__ int h[NBUCKETS];
    if (blockIdx.x < NB) {
        int* my = row_cnt8 + (size_t)(blockIdx.x & (NHCOPY - 1)) * NROWS_PAD;
        for (int i = threadIdx.x; i < NBUCKETS; i += blockDim.x) h[i] = 0;
        __syncthreads();
        int stride = NB * blockDim.x;
        for (int e = blockIdx.x * blockDim.x + threadIdx.x; e < n_edges; e += stride) {
            int r = rows[e];
            atomicAdd(&h[((unsigned)r) >> BSHIFT], 1);
            atomicAdd(&my[r], 1);        // own-XCD copy: lines stay L2-resident
        }
        __syncthreads();
        for (int i = threadIdx.x; i < NBUCKETS; i += blockDim.x)
            partial[blockIdx.x * NBUCKETS + i] = h[i];
    } else {
        int g = (blockIdx.x - NB) * blockDim.x + threadIdx.x;  // group of 4
        long base = (long)g * 4;
        if (base >= (long)N_NODES * DIM) return;
        const float* src;
        long off;
        if (base < (long)N_USERS * DIM)                 { src = uemb; off = base; }
        else if (base < (long)(N_USERS + N_ITEMS) * DIM){ src = iemb; off = base - (long)N_USERS * DIM; }
        else                                            { src = temb; off = base - (long)(N_USERS + N_ITEMS) * DIM; }
        float4 v = *(const float4*)(src + off);
        __half2 a = __floats2half2_rn(v.x, v.y);
        __half2 b = __floats2half2_rn(v.z, v.w);
        uint2 o;
        o.x = *(unsigned*)&a;
        o.y = *(unsigned*)&b;
        ((uint2*)h0)[g] = o;
    }
}

// Logical L = bucket*NB + block; physical = block*NBUCKETS + bucket.
__device__ __forceinline__ int phys_idx(int L) {
    return (L & (NB - 1)) * NBUCKETS + (L >> NBSHIFT);
}

__global__ void scanB1_kernel(const int* __restrict__ partial,
                              int* __restrict__ psum) {
    __shared__ int s[256];
    int tid = threadIdx.x;
    int c0 = blockIdx.x * CH;
    int c1 = min(M_TOT, c0 + CH);
    int sum = 0;
    for (int L = c0 + tid; L < c1; L += 256) sum += partial[phys_idx(L)];
    s[tid] = sum;
    __syncthreads();
    for (int off = 128; off > 0; off >>= 1) {
        if (tid < off) s[tid] += s[tid + off];
        __syncthreads();
    }
    if (tid == 0) psum[blockIdx.x] = s[0];
}

// scanB2 folded in: each block reduces psum[0..bid) itself (256 ints, cheap).
__global__ void scanB3_kernel(const int* __restrict__ partial,
                              const int* __restrict__ psum,
                              int* __restrict__ offs) {
    __shared__ int s[SB];
    __shared__ int tile[256];
    __shared__ int carry;
    int tid = threadIdx.x;
    s[tid] = (tid < blockIdx.x) ? psum[tid] : 0;
    __syncthreads();
    for (int off = 128; off > 0; off >>= 1) {
        if (tid < off) s[tid] += s[tid + off];
        __syncthreads();
    }
    if (tid == 0) carry = s[0];
    __syncthreads();
    int c0 = blockIdx.x * CH;
    int c1 = min(M_TOT, c0 + CH);
    for (int base = c0; base < c1; base += 256) {
        int L = base + tid;
        int v = (L < c1) ? partial[phys_idx(L)] : 0;
        tile[tid] = v;
        __syncthreads();
        for (int off = 1; off < 256; off <<= 1) {
            int t = (tid >= off) ? tile[tid - off] : 0;
            __syncthreads();
            tile[tid] += t;
            __syncthreads();
        }
        if (L < c1) offs[L] = carry + tile[tid] - v;
        __syncthreads();
        if (tid == 255) carry += tile[255];
        __syncthreads();
    }
}

__device__ __forceinline__ int pad8(int x) { return (x + 7) & ~7; }

// One 512-thread block per bucket: sum the 8 hist copies, pad8-scan the
// 1024 row counts (bucket base FIXED at b*BUCKET_CAP -> independent),
// emit row_span, zero-fill the pad slots.
__global__ void scanR_kernel(const int* __restrict__ row_cnt8,
                             int2* __restrict__ row_span,
                             int2* __restrict__ csr_cv) {
    __shared__ int lcnt[BROWS];
    __shared__ int s[512];
    int b = blockIdx.x;
    int t = threadIdx.x;
    int rbase = b << BSHIFT;
    int c0s = 0, c1s = 0;
    #pragma unroll
    for (int c = 0; c < NHCOPY; ++c) {
        const int* cp = row_cnt8 + (size_t)c * NROWS_PAD + rbase;
        c0s += cp[t];
        c1s += cp[t + 512];
    }
    lcnt[t]       = c0s;
    lcnt[t + 512] = c1s;
    __syncthreads();
    s[t] = pad8(lcnt[2 * t]) + pad8(lcnt[2 * t + 1]);
    __syncthreads();
    for (int off = 1; off < 512; off <<= 1) {
        int v = (t >= off) ? s[t - off] : 0;
        __syncthreads();
        s[t] += v;                       // inclusive over pairs
        __syncthreads();
    }
    int base = b * BUCKET_CAP + (t ? s[t - 1] : 0);
    int c0 = lcnt[2 * t];
    int c1 = lcnt[2 * t + 1];
    int pe = pad8(c0);
    int po = pad8(c1);
    int p_even = base;
    int p_odd  = base + pe;
    int2 sp0; sp0.x = p_even; sp0.y = p_even + pe;
    int2 sp1; sp1.x = p_odd;  sp1.y = p_odd + po;
    row_span[rbase + 2 * t]     = sp0;
    row_span[rbase + 2 * t + 1] = sp1;
    int2 z; z.x = 0; z.y = 0;
    for (int k = c0; k < pe; ++k) csr_cv[p_even + k] = z;
    for (int k = c1; k < po; ++k) csr_cv[p_odd + k]  = z;
}

// Bin edges into 1024-row buckets at exact positions; LDS-only atomics.
// 512 threads/block, grid fixed at NB (mapping must match prep hist part).
__global__ void scatter1_kernel(const int* __restrict__ rows,
                                const int* __restrict__ cols,
                                const float* __restrict__ vals,
                                const int* __restrict__ offs,
                                int2* __restrict__ bkt_buf, int n_edges) {
    __shared__ int lpos[NBUCKETS];
    for (int i = threadIdx.x; i < NBUCKETS; i += blockDim.x)
        lpos[i] = offs[i * NB + blockIdx.x];
    __syncthreads();
    int stride = gridDim.x * blockDim.x;
    for (int e = blockIdx.x * blockDim.x + threadIdx.x; e < n_edges; e += stride) {
        int r = rows[e];
        int b = ((unsigned)r) >> BSHIFT;
        int pos = atomicAdd(&lpos[b], 1);
        int2 p;
        p.x = cols[e] | ((r & (BROWS - 1)) << 19);   // 19+10 bits < 32
        p.y = __float_as_int(vals[e]);
        bkt_buf[pos] = p;
    }
}

// Placement-only pass: ONE 1024-thread block per bucket (single-XCD writes
// per 196 KB window -> no cross-XCD line bouncing), LDS row cursors seeded
// from row_span (no hist pass: bkt_buf is read exactly ONCE).
__global__ void scatter2_kernel(const int2* __restrict__ bkt_buf,
                                const int* __restrict__ offs,
                                const int2* __restrict__ row_span,
                                int2* __restrict__ csr_cv, int n_edges) {
    __shared__ int lptr[BROWS];
    __shared__ int lfill[BROWS];
    int b = blockIdx.x;
    int t = threadIdx.x;
    int rbase = b << BSHIFT;
    lptr[t]  = row_span[rbase + t].x;
    lfill[t] = 0;
    __syncthreads();
    int e0 = offs[b * NB];
    int e1 = (b == NBUCKETS - 1) ? n_edges : offs[(b + 1) * NB];
    for (int e = e0 + t; e < e1; e += blockDim.x) {
        int2 p = bkt_buf[e];
        int delta = ((unsigned)p.x) >> 19;
        int pos = lptr[delta] + atomicAdd(&lfill[delta], 1);
        int2 cv;
        cv.x = p.x & COLMASK;
        cv.y = p.y;
        csr_cv[pos] = cv;
    }
}

// ---------- SpMV helpers ----------
// fmaf(half2float(h), w, acc) lowers to v_fma_mix_f32 (fp16 src, fp32 MAC).
__device__ __forceinline__ float4 fma_mix4(const ushort* __restrict__ h,
                                           int row, int l16, float w,
                                           float4 acc) {
    uint2 r = ((const uint2*)(h + (size_t)row * DIM))[l16];
    __half2 h01 = *(__half2*)&r.x;
    __half2 h23 = *(__half2*)&r.y;
    acc.x = __builtin_fmaf(__half2float(__low2half(h01)),  w, acc.x);
    acc.y = __builtin_fmaf(__half2float(__high2half(h01)), w, acc.y);
    acc.z = __builtin_fmaf(__half2float(__low2half(h23)),  w, acc.z);
    acc.w = __builtin_fmaf(__half2float(__high2half(h23)), w, acc.w);
    return acc;
}

// Process one 8-edge batch: 4 unconditional int4 loads (rows are padded to
// a multiple of 8 with zero-val entries -> no clamps, no ternaries).
__device__ __forceinline__ float4 batch8(const int2* __restrict__ csr_cv,
                                         const ushort* __restrict__ h_src,
                                         int p, int l16, float4 acc) {
    const int4* q = (const int4*)(csr_cv + p);
    int4 a = q[0], b = q[1], c = q[2], d = q[3];
    acc = fma_mix4(h_src, a.x, l16, __int_as_float(a.y), acc);
    acc = fma_mix4(h_src, a.z, l16, __int_as_float(a.w), acc);
    acc = fma_mix4(h_src, b.x, l16, __int_as_float(b.y), acc);
    acc = fma_mix4(h_src, b.z, l16, __int_as_float(b.w), acc);
    acc = fma_mix4(h_src, c.x, l16, __int_as_float(c.y), acc);
    acc = fma_mix4(h_src, c.z, l16, __int_as_float(c.w), acc);
    acc = fma_mix4(h_src, d.x, l16, __int_as_float(d.y), acc);
    acc = fma_mix4(h_src, d.z, l16, __int_as_float(d.w), acc);
    return acc;
}

#define NWAVES ((N_NODES + 3) / 4)    // spmv waves; tail waves do the gather

// Full-table SpMV: 4 rows/wave (1 per 16-lane group), 8 edges in flight.
// (8-unroll is the proven optimum.) Tail waves perform the fused batch-row
// gather of h_src (u_acc/it_acc init or add).
__global__ void spmv_csr_kernel(const int2* __restrict__ row_span,
                                const int2* __restrict__ csr_cv,
                                const ushort* __restrict__ h_src,
                                ushort* __restrict__ h_dst,
                                const int* __restrict__ users,
                                const int* __restrict__ items,
                                float* __restrict__ u_acc,
                                float* __restrict__ it_acc,
                                int B, int first) {
    int wave = (int)(((long)blockIdx.x * blockDim.x + threadIdx.x) >> 6);
    int lane = threadIdx.x & 63;
    int g    = lane >> 4;
    int l16  = lane & 15;
    if (wave < NWAVES) {
        int r    = wave * 4 + g;
        int rc   = min(r, N_NODES - 1);
        int2 sp  = row_span[rc];
        int p0   = sp.x;
        int len  = (r < N_NODES) ? (sp.y - sp.x) : 0;   // multiple of 8
        int m = max(len, __shfl_xor(len, 16, 64));
        m = max(m, __shfl_xor(m, 32, 64));
        float4 acc = make_float4(0.f, 0.f, 0.f, 0.f);
        for (int off = 0; off < m; off += 8) {
            if (off < len)
                acc = batch8(csr_cv, h_src, p0 + off, l16, acc);
        }
        if (r < N_NODES) {
            __half2 a = __floats2half2_rn(acc.x, acc.y);
            __half2 b = __floats2half2_rn(acc.z, acc.w);
            uint2 o;
            o.x = *(unsigned*)&a;
            o.y = *(unsigned*)&b;
            ((uint2*)(h_dst + (size_t)r * DIM))[l16] = o;
        }
    } else {
        int s = (wave - NWAVES) * 4 + g;
        if (s >= 2 * B) return;
        int node = (s < B) ? users[s] : (N_USERS + items[s - B]);
        uint2 hr = ((const uint2*)(h_src + (size_t)node * DIM))[l16];
        float2 a01 = __half22float2(*(__half2*)&hr.x);
        float2 a23 = __half22float2(*(__half2*)&hr.y);
        float* dst = (s < B) ? (u_acc + (size_t)s * DIM)
                             : (it_acc + (size_t)(s - B) * DIM);
        float4* p = (float4*)dst + l16;
        if (first) {
            *p = make_float4(a01.x, a01.y, a23.x, a23.y);
        } else {
            float4 o = *p;
            o.x += a01.x; o.y += a01.y; o.z += a23.x; o.w += a23.y;
            *p = o;
        }
    }
}

// Layer-3 SpMV over BATCH ROWS ONLY; acc initialized with the h2 fragment
// (fuses the final gather_add).
__global__ void spmv_batch_kernel(const int2* __restrict__ row_span,
                                  const int2* __restrict__ csr_cv,
                                  const ushort* __restrict__ h_src,
                                  const int* __restrict__ users,
                                  const int* __restrict__ items,
                                  float* __restrict__ u_acc,
                                  float* __restrict__ it_acc, int B) {
    int wave = (int)(((long)blockIdx.x * blockDim.x + threadIdx.x) >> 6);
    int lane = threadIdx.x & 63;
    int g    = lane >> 4;
    int l16  = lane & 15;
    int s    = wave * 4 + g;
    bool ok  = s < 2 * B;
    int node = 0;
    if (ok) node = (s < B) ? users[s] : (N_USERS + items[s - B]);
    float4 acc = make_float4(0.f, 0.f, 0.f, 0.f);
    if (ok) {
        uint2 hr = ((const uint2*)(h_src + (size_t)node * DIM))[l16];
        float2 a01 = __half22float2(*(__half2*)&hr.x);
        float2 a23 = __half22float2(*(__half2*)&hr.y);
        acc = make_float4(a01.x, a01.y, a23.x, a23.y);
    }
    int2 sp  = row_span[node];
    int p0   = sp.x;
    int len  = ok ? (sp.y - sp.x) : 0;
    int m = max(len, __shfl_xor(len, 16, 64));
    m = max(m, __shfl_xor(m, 32, 64));
    for (int off = 0; off < m; off += 8) {
        if (off < len)
            acc = batch8(csr_cv, h_src, p0 + off, l16, acc);
    }
    if (ok) {
        float* dst = (s < B) ? (u_acc + (size_t)s * DIM)
                             : (it_acc + (size_t)(s - B) * DIM);
        float4* p = (float4*)dst + l16;
        float4 old = *p;
        old.x += acc.x; old.y += acc.y; old.z += acc.z; old.w += acc.w;
        *p = old;
    }
}

__global__ void dot_kernel(const float* __restrict__ u_acc,
                           const float* __restrict__ it_acc,
                           float* __restrict__ out, int B) {
    int gid  = blockIdx.x * blockDim.x + threadIdx.x;
    int b    = gid >> 6;
    int lane = gid & 63;
    if (b >= B) return;
    float p = u_acc[(size_t)b * DIM + lane] * it_acc[(size_t)b * DIM + lane];
    #pragma unroll
    for (int off = 32; off > 0; off >>= 1)
        p += __shfl_down(p, off, 64);
    if (lane == 0) out[b] = p * (1.0f / 16.0f);
}

extern "C" void kernel_launch(void* const* d_in, const int* in_sizes, int n_in,
                              void* d_out, int out_size, void* d_ws, size_t ws_size,
                              hipStream_t stream) {
    const int*   users = (const int*)d_in[0];
    const int*   items = (const int*)d_in[1];
    const int*   erows = (const int*)d_in[2];
    const int*   ecols = (const int*)d_in[3];
    const float* evals = (const float*)d_in[4];
    const float* uemb  = (const float*)d_in[5];
    const float* iemb  = (const float*)d_in[6];
    const float* temb  = (const float*)d_in[7];
    float* out = (float*)d_out;

    const int n_edges = in_sizes[2];
    const int B       = in_sizes[0];

    const size_t h2bytes = (((size_t)N_NODES * DIM * 2 + 255) / 256) * 256;  // 38.4 MB
    const size_t abytes  = (size_t)B * DIM * sizeof(float);                  // 4.2 MB
    const size_t spbytes = (((size_t)NROWS_PAD * 8 + 255) / 256) * 256;      // 2.4 MB
    const size_t csrbytes= (size_t)NBUCKETS * BUCKET_CAP * 8;                // 57.8 MB
    const size_t bkbytes = (size_t)n_edges * 8;                              // 40 MB
    const size_t mbytes  = (((size_t)M_TOT * 4 + 255) / 256) * 256;          // 0.6 MB
    const size_t cbytes8 = (((size_t)NROWS_PAD * NHCOPY * 4 + 255) / 256) * 256; // 9.6 MB

    char* ws = (char*)d_ws;
    size_t off = 0;
    ushort* hA       = (ushort*)(ws + off); off += h2bytes;
    ushort* hB       = (ushort*)(ws + off); off += h2bytes;
    float*  u_acc    = (float*) (ws + off); off += abytes;
    float*  it_acc   = (float*) (ws + off); off += abytes;
    int2*   row_span = (int2*)  (ws + off); off += spbytes;
    int2*   csr_cv   = (int2*)  (ws + off); off += csrbytes;
    int2*   bkt_buf  = (int2*)  (ws + off); off += bkbytes;
    int*    partial  = (int*)   (ws + off); off += mbytes;
    int*    offs     = (int*)   (ws + off); off += mbytes;
    int*    row_cnt8 = (int*)   (ws + off); off += cbytes8;
    int*    psum     = (int*)   (ws + off); off += 4096;   // ~198 MB total

    dim3 blk(256);
    dim3 blk512(512);
    dim3 blk1k(1024);

    // ---- CSR build + h0 concat fused into hist pass ----
    hipMemsetAsync(row_cnt8, 0, (size_t)NROWS_PAD * NHCOPY * 4, stream);
    const long n4 = (long)N_NODES * DIM / 4;
    const int  nconcat = (int)((n4 + 511) / 512);
    prep_kernel<<<NB + nconcat, blk512, 0, stream>>>(erows, partial, row_cnt8,
                                                     n_edges, uemb, iemb, temb, hA);
    scanB1_kernel<<<SB, blk, 0, stream>>>(partial, psum);
    scanB3_kernel<<<SB, blk, 0, stream>>>(partial, psum, offs);
    scanR_kernel<<<NBUCKETS, blk512, 0, stream>>>(row_cnt8, row_span, csr_cv);
    scatter1_kernel<<<NB, blk512, 0, stream>>>(erows, ecols, evals, offs, bkt_buf, n_edges);
    scatter2_kernel<<<NBUCKETS, blk1k, 0, stream>>>(bkt_buf, offs, row_span,
                                                    csr_cv, n_edges);

    // ---- layers 1,2: full-table SpMV (+fused batch gather of h_src);
    //      layer 3: batch rows only (+fused h2 gather via acc init) ----
    const int gwaves  = (2 * B + 3) / 4;
    const int fblocks = (int)(((long)(NWAVES + gwaves) * 64 + 255) / 256);
    spmv_csr_kernel<<<fblocks, blk, 0, stream>>>(row_span, csr_cv, hA, hB,
                                                 users, items, u_acc, it_acc, B, 1);
    spmv_csr_kernel<<<fblocks, blk, 0, stream>>>(row_span, csr_cv, hB, hA,
                                                 users, items, u_acc, it_acc, B, 0);
    const int bblocks = (int)(((long)gwaves * 64 + 255) / 256);
    spmv_batch_kernel<<<bblocks, blk, 0, stream>>>(row_span, csr_cv, hA,
                                                   users, items, u_acc, it_acc, B);

    dot_kernel<<<(B * 64 + 255) / 256, blk, 0, stream>>>(u_acc, it_acc, out, B);
}

// Round 11
// 520.092 us; speedup vs baseline: 1.7147x; 1.3386x over previous
//
#include <hip/hip_runtime.h>
#include <hip/hip_fp16.h>

#define N_USERS  200000
#define N_ITEMS  100000
#define N_TOPICS 100
#define N_NODES  (N_USERS + N_ITEMS + N_TOPICS)
#define DIM      64
#define BSHIFT   10                               // 1024 rows per bucket
#define BROWS    (1 << BSHIFT)
#define NBUCKETS ((N_NODES + BROWS - 1) >> BSHIFT)   // 294
#define NROWS_PAD (NBUCKETS * BROWS)              // 301,056
#define COLMASK  0x7FFFF                          // 19 bits (N_NODES < 2^19)
#define NB       512                              // binning blocks
#define NBSHIFT  9
#define M_TOT    (NBUCKETS * NB)                  // 150,528 partials
#define SB       256                              // scan blocks
#define CH       ((M_TOT + SB - 1) / SB)
// Padded-CSR: each row padded to a multiple of 8 edges (zero-val entries);
// each bucket owns a fixed region. Bucket padded total ~20650 +- ~140 (28
// sigma below 24576) -> no overflow for this dataset family.
#define BUCKET_CAP 24576

// Memory-system rules learned (r4/r6/r8/r9/r10):
//  - Scattered global ATOMICS write through the per-XCD L2 to the coherent
//    point: ~30-40 B fabric write per 4 B atomic, location-independent
//    (r9 vs r10: NHCOPY=8 privatization changed WRITE_SIZE by 0). Never
//    use scattered global atomics on hot paths; LDS atomics are fine.
//  - Scattered sub-line STORES amplify ~5-8x unless the destination
//    window's active lines fit per-XCD L2 AND one block (one XCD) owns
//    each window (r6: BSHIFT=10 for scatter1 cursors; r8: S2SPLIT=8
//    sharing a bucket window cost 275 MB for 48 MB payload).

// ---------- prep: bucket hist (blocks [0,NB)) + h0 concat (rest) ----------

__global__ void prep_kernel(const int* __restrict__ rows,
                            int* __restrict__ partial, int n_edges,
                            const float* __restrict__ uemb,
                            const float* __restrict__ iemb,
                            const float* __restrict__ temb,
                            ushort* __restrict__ h0) {
    __shared__ int h[NBUCKETS];
    if (blockIdx.x < NB) {
        for (int i = threadIdx.x; i < NBUCKETS; i += blockDim.x) h[i] = 0;
        __syncthreads();
        int stride = NB * blockDim.x;
        for (int e = blockIdx.x * blockDim.x + threadIdx.x; e < n_edges; e += stride)
            atomicAdd(&h[((unsigned)rows[e]) >> BSHIFT], 1);
        __syncthreads();
        for (int i = threadIdx.x; i < NBUCKETS; i += blockDim.x)
            partial[blockIdx.x * NBUCKETS + i] = h[i];
    } else {
        int g = (blockIdx.x - NB) * blockDim.x + threadIdx.x;  // group of 4
        long base = (long)g * 4;
        if (base >= (long)N_NODES * DIM) return;
        const float* src;
        long off;
        if (base < (long)N_USERS * DIM)                 { src = uemb; off = base; }
        else if (base < (long)(N_USERS + N_ITEMS) * DIM){ src = iemb; off = base - (long)N_USERS * DIM; }
        else                                            { src = temb; off = base - (long)(N_USERS + N_ITEMS) * DIM; }
        float4 v = *(const float4*)(src + off);
        __half2 a = __floats2half2_rn(v.x, v.y);
        __half2 b = __floats2half2_rn(v.z, v.w);
        uint2 o;
        o.x = *(unsigned*)&a;
        o.y = *(unsigned*)&b;
        ((uint2*)h0)[g] = o;
    }
}

// Logical L = bucket*NB + block; physical = block*NBUCKETS + bucket.
__device__ __forceinline__ int phys_idx(int L) {
    return (L & (NB - 1)) * NBUCKETS + (L >> NBSHIFT);
}

__global__ void scanB1_kernel(const int* __restrict__ partial,
                              int* __restrict__ psum) {
    __shared__ int s[256];
    int tid = threadIdx.x;
    int c0 = blockIdx.x * CH;
    int c1 = min(M_TOT, c0 + CH);
    int sum = 0;
    for (int L = c0 + tid; L < c1; L += 256) sum += partial[phys_idx(L)];
    s[tid] = sum;
    __syncthreads();
    for (int off = 128; off > 0; off >>= 1) {
        if (tid < off) s[tid] += s[tid + off];
        __syncthreads();
    }
    if (tid == 0) psum[blockIdx.x] = s[0];
}

// scanB2 folded in: each block reduces psum[0..bid) itself (256 ints, cheap).
__global__ void scanB3_kernel(const int* __restrict__ partial,
                              const int* __restrict__ psum,
                              int* __restrict__ offs) {
    __shared__ int s[SB];
    __shared__ int tile[256];
    __shared__ int carry;
    int tid = threadIdx.x;
    s[tid] = (tid < blockIdx.x) ? psum[tid] : 0;
    __syncthreads();
    for (int off = 128; off > 0; off >>= 1) {
        if (tid < off) s[tid] += s[tid + off];
        __syncthreads();
    }
    if (tid == 0) carry = s[0];
    __syncthreads();
    int c0 = blockIdx.x * CH;
    int c1 = min(M_TOT, c0 + CH);
    for (int base = c0; base < c1; base += 256) {
        int L = base + tid;
        int v = (L < c1) ? partial[phys_idx(L)] : 0;
        tile[tid] = v;
        __syncthreads();
        for (int off = 1; off < 256; off <<= 1) {
            int t = (tid >= off) ? tile[tid - off] : 0;
            __syncthreads();
            tile[tid] += t;
            __syncthreads();
        }
        if (L < c1) offs[L] = carry + tile[tid] - v;
        __syncthreads();
        if (tid == 255) carry += tile[255];
        __syncthreads();
    }
}

// Bin edges into 1024-row buckets at exact positions; LDS-only atomics.
// 512 threads/block, grid fixed at NB (mapping must match prep hist part).
__global__ void scatter1_kernel(const int* __restrict__ rows,
                                const int* __restrict__ cols,
                                const float* __restrict__ vals,
                                const int* __restrict__ offs,
                                int2* __restrict__ bkt_buf, int n_edges) {
    __shared__ int lpos[NBUCKETS];
    for (int i = threadIdx.x; i < NBUCKETS; i += blockDim.x)
        lpos[i] = offs[i * NB + blockIdx.x];
    __syncthreads();
    int stride = gridDim.x * blockDim.x;
    for (int e = blockIdx.x * blockDim.x + threadIdx.x; e < n_edges; e += stride) {
        int r = rows[e];
        int b = ((unsigned)r) >> BSHIFT;
        int pos = atomicAdd(&lpos[b], 1);
        int2 p;
        p.x = cols[e] | ((r & (BROWS - 1)) << 19);   // 19+10 bits < 32
        p.y = __float_as_int(vals[e]);
        bkt_buf[pos] = p;
    }
}

__device__ __forceinline__ int pad8(int x) { return (x + 7) & ~7; }

// One 1024-thread block per 1024-row bucket (one thread per row counter):
// LDS row hist from bkt_buf, pad8 scan (512 scan threads, 2 rows each),
// emit row_span, place edges into the bucket's fixed csr window (single
// block = single XCD per window), zero-fill pad slots (1 row/thread).
__global__ void scatter2_kernel(const int2* __restrict__ bkt_buf,
                                const int* __restrict__ offs,
                                int2* __restrict__ row_span,
                                int2* __restrict__ csr_cv, int n_edges) {
    __shared__ int lcnt[BROWS];
    __shared__ int lptr[BROWS];
    __shared__ int lfill[BROWS];
    __shared__ int s[512];
    int b = blockIdx.x;
    int t = threadIdx.x;
    int e0 = offs[b * NB];
    int e1 = (b == NBUCKETS - 1) ? n_edges : offs[(b + 1) * NB];
    lcnt[t]  = 0;
    lfill[t] = 0;
    __syncthreads();
    for (int e = e0 + t; e < e1; e += 1024)
        atomicAdd(&lcnt[((unsigned)bkt_buf[e].x) >> 19], 1);
    __syncthreads();
    if (t < 512) s[t] = pad8(lcnt[2 * t]) + pad8(lcnt[2 * t + 1]);
    __syncthreads();
    for (int off = 1; off < 512; off <<= 1) {
        int v = 0;
        if (t < 512 && t >= off) v = s[t - off];
        __syncthreads();
        if (t < 512) s[t] += v;          // inclusive over pairs
        __syncthreads();
    }
    if (t < 512) {
        int base = b * BUCKET_CAP + (t ? s[t - 1] : 0);
        int rbase = b << BSHIFT;
        int pe = pad8(lcnt[2 * t]);
        int po = pad8(lcnt[2 * t + 1]);
        int p_even = base;
        int p_odd  = base + pe;
        lptr[2 * t]     = p_even;
        lptr[2 * t + 1] = p_odd;
        int2 sp0; sp0.x = p_even; sp0.y = p_even + pe;
        int2 sp1; sp1.x = p_odd;  sp1.y = p_odd + po;
        row_span[rbase + 2 * t]     = sp0;   // rows >= N_NODES: len 0, harmless
        row_span[rbase + 2 * t + 1] = sp1;
    }
    __syncthreads();
    for (int e = e0 + t; e < e1; e += 1024) {
        int2 p = bkt_buf[e];
        int delta = ((unsigned)p.x) >> 19;
        int pos = lptr[delta] + atomicAdd(&lfill[delta], 1);
        int2 cv;
        cv.x = p.x & COLMASK;
        cv.y = p.y;
        csr_cv[pos] = cv;
    }
    __syncthreads();
    // zero-fill pad slots (col 0, val 0): one row per thread, <=7 each
    {
        int c  = lcnt[t];
        int cp = pad8(c);
        int p  = lptr[t];
        int2 z; z.x = 0; z.y = 0;
        for (int k = c; k < cp; ++k) csr_cv[p + k] = z;
    }
}

// ---------- SpMV helpers ----------
// fmaf(half2float(h), w, acc) lowers to v_fma_mix_f32 (fp16 src, fp32 MAC).
__device__ __forceinline__ float4 fma_mix4(const ushort* __restrict__ h,
                                           int row, int l16, float w,
                                           float4 acc) {
    uint2 r = ((const uint2*)(h + (size_t)row * DIM))[l16];
    __half2 h01 = *(__half2*)&r.x;
    __half2 h23 = *(__half2*)&r.y;
    acc.x = __builtin_fmaf(__half2float(__low2half(h01)),  w, acc.x);
    acc.y = __builtin_fmaf(__half2float(__high2half(h01)), w, acc.y);
    acc.z = __builtin_fmaf(__half2float(__low2half(h23)),  w, acc.z);
    acc.w = __builtin_fmaf(__half2float(__high2half(h23)), w, acc.w);
    return acc;
}

// Process one 8-edge batch: 4 unconditional int4 loads (rows are padded to
// a multiple of 8 with zero-val entries -> no clamps, no ternaries).
__device__ __forceinline__ float4 batch8(const int2* __restrict__ csr_cv,
                                         const ushort* __restrict__ h_src,
                                         int p, int l16, float4 acc) {
    const int4* q = (const int4*)(csr_cv + p);
    int4 a = q[0], b = q[1], c = q[2], d = q[3];
    acc = fma_mix4(h_src, a.x, l16, __int_as_float(a.y), acc);
    acc = fma_mix4(h_src, a.z, l16, __int_as_float(a.w), acc);
    acc = fma_mix4(h_src, b.x, l16, __int_as_float(b.y), acc);
    acc = fma_mix4(h_src, b.z, l16, __int_as_float(b.w), acc);
    acc = fma_mix4(h_src, c.x, l16, __int_as_float(c.y), acc);
    acc = fma_mix4(h_src, c.z, l16, __int_as_float(c.w), acc);
    acc = fma_mix4(h_src, d.x, l16, __int_as_float(d.y), acc);
    acc = fma_mix4(h_src, d.z, l16, __int_as_float(d.w), acc);
    return acc;
}

#define NWAVES ((N_NODES + 3) / 4)    // spmv waves; tail waves do the gather

// Full-table SpMV: 4 rows/wave (1 per 16-lane group), 8 edges in flight.
// (8-unroll is the proven optimum.) Tail waves perform the fused batch-row
// gather of h_src (u_acc/it_acc init or add).
__global__ void spmv_csr_kernel(const int2* __restrict__ row_span,
                                const int2* __restrict__ csr_cv,
                                const ushort* __restrict__ h_src,
                                ushort* __restrict__ h_dst,
                                const int* __restrict__ users,
                                const int* __restrict__ items,
                                float* __restrict__ u_acc,
                                float* __restrict__ it_acc,
                                int B, int first) {
    int wave = (int)(((long)blockIdx.x * blockDim.x + threadIdx.x) >> 6);
    int lane = threadIdx.x & 63;
    int g    = lane >> 4;
    int l16  = lane & 15;
    if (wave < NWAVES) {
        int r    = wave * 4 + g;
        int rc   = min(r, N_NODES - 1);
        int2 sp  = row_span[rc];
        int p0   = sp.x;
        int len  = (r < N_NODES) ? (sp.y - sp.x) : 0;   // multiple of 8
        int m = max(len, __shfl_xor(len, 16, 64));
        m = max(m, __shfl_xor(m, 32, 64));
        float4 acc = make_float4(0.f, 0.f, 0.f, 0.f);
        for (int off = 0; off < m; off += 8) {
            if (off < len)
                acc = batch8(csr_cv, h_src, p0 + off, l16, acc);
        }
        if (r < N_NODES) {
            __half2 a = __floats2half2_rn(acc.x, acc.y);
            __half2 b = __floats2half2_rn(acc.z, acc.w);
            uint2 o;
            o.x = *(unsigned*)&a;
            o.y = *(unsigned*)&b;
            ((uint2*)(h_dst + (size_t)r * DIM))[l16] = o;
        }
    } else {
        int s = (wave - NWAVES) * 4 + g;
        if (s >= 2 * B) return;
        int node = (s < B) ? users[s] : (N_USERS + items[s - B]);
        uint2 hr = ((const uint2*)(h_src + (size_t)node * DIM))[l16];
        float2 a01 = __half22float2(*(__half2*)&hr.x);
        float2 a23 = __half22float2(*(__half2*)&hr.y);
        float* dst = (s < B) ? (u_acc + (size_t)s * DIM)
                             : (it_acc + (size_t)(s - B) * DIM);
        float4* p = (float4*)dst + l16;
        if (first) {
            *p = make_float4(a01.x, a01.y, a23.x, a23.y);
        } else {
            float4 o = *p;
            o.x += a01.x; o.y += a01.y; o.z += a23.x; o.w += a23.y;
            *p = o;
        }
    }
}

// Layer-3 SpMV over BATCH ROWS ONLY; acc initialized with the h2 fragment
// (fuses the final gather_add).
__global__ void spmv_batch_kernel(const int2* __restrict__ row_span,
                                  const int2* __restrict__ csr_cv,
                                  const ushort* __restrict__ h_src,
                                  const int* __restrict__ users,
                                  const int* __restrict__ items,
                                  float* __restrict__ u_acc,
                                  float* __restrict__ it_acc, int B) {
    int wave = (int)(((long)blockIdx.x * blockDim.x + threadIdx.x) >> 6);
    int lane = threadIdx.x & 63;
    int g    = lane >> 4;
    int l16  = lane & 15;
    int s    = wave * 4 + g;
    bool ok  = s < 2 * B;
    int node = 0;
    if (ok) node = (s < B) ? users[s] : (N_USERS + items[s - B]);
    float4 acc = make_float4(0.f, 0.f, 0.f, 0.f);
    if (ok) {
        uint2 hr = ((const uint2*)(h_src + (size_t)node * DIM))[l16];
        float2 a01 = __half22float2(*(__half2*)&hr.x);
        float2 a23 = __half22float2(*(__half2*)&hr.y);
        acc = make_float4(a01.x, a01.y, a23.x, a23.y);
    }
    int2 sp  = row_span[node];
    int p0   = sp.x;
    int len  = ok ? (sp.y - sp.x) : 0;
    int m = max(len, __shfl_xor(len, 16, 64));
    m = max(m, __shfl_xor(m, 32, 64));
    for (int off = 0; off < m; off += 8) {
        if (off < len)
            acc = batch8(csr_cv, h_src, p0 + off, l16, acc);
    }
    if (ok) {
        float* dst = (s < B) ? (u_acc + (size_t)s * DIM)
                             : (it_acc + (size_t)(s - B) * DIM);
        float4* p = (float4*)dst + l16;
        float4 old = *p;
        old.x += acc.x; old.y += acc.y; old.z += acc.z; old.w += acc.w;
        *p = old;
    }
}

__global__ void dot_kernel(const float* __restrict__ u_acc,
                           const float* __restrict__ it_acc,
                           float* __restrict__ out, int B) {
    int gid  = blockIdx.x * blockDim.x + threadIdx.x;
    int b    = gid >> 6;
    int lane = gid & 63;
    if (b >= B) return;
    float p = u_acc[(size_t)b * DIM + lane] * it_acc[(size_t)b * DIM + lane];
    #pragma unroll
    for (int off = 32; off > 0; off >>= 1)
        p += __shfl_down(p, off, 64);
    if (lane == 0) out[b] = p * (1.0f / 16.0f);
}

extern "C" void kernel_launch(void* const* d_in, const int* in_sizes, int n_in,
                              void* d_out, int out_size, void* d_ws, size_t ws_size,
                              hipStream_t stream) {
    const int*   users = (const int*)d_in[0];
    const int*   items = (const int*)d_in[1];
    const int*   erows = (const int*)d_in[2];
    const int*   ecols = (const int*)d_in[3];
    const float* evals = (const float*)d_in[4];
    const float* uemb  = (const float*)d_in[5];
    const float* iemb  = (const float*)d_in[6];
    const float* temb  = (const float*)d_in[7];
    float* out = (float*)d_out;

    const int n_edges = in_sizes[2];
    const int B       = in_sizes[0];

    const size_t h2bytes = (((size_t)N_NODES * DIM * 2 + 255) / 256) * 256;  // 38.4 MB
    const size_t abytes  = (size_t)B * DIM * sizeof(float);                  // 4.2 MB
    const size_t spbytes = (((size_t)NROWS_PAD * 8 + 255) / 256) * 256;      // 2.4 MB
    const size_t csrbytes= (size_t)NBUCKETS * BUCKET_CAP * 8;                // 57.8 MB
    const size_t bkbytes = (size_t)n_edges * 8;                              // 40 MB
    const size_t mbytes  = (((size_t)M_TOT * 4 + 255) / 256) * 256;          // 0.6 MB

    char* ws = (char*)d_ws;
    size_t off = 0;
    ushort* hA       = (ushort*)(ws + off); off += h2bytes;
    ushort* hB       = (ushort*)(ws + off); off += h2bytes;
    float*  u_acc    = (float*) (ws + off); off += abytes;
    float*  it_acc   = (float*) (ws + off); off += abytes;
    int2*   row_span = (int2*)  (ws + off); off += spbytes;
    int2*   csr_cv   = (int2*)  (ws + off); off += csrbytes;
    int2*   bkt_buf  = (int2*)  (ws + off); off += bkbytes;
    int*    partial  = (int*)   (ws + off); off += mbytes;
    int*    offs     = (int*)   (ws + off); off += mbytes;
    int*    psum     = (int*)   (ws + off); off += 4096;   // ~189 MB total

    dim3 blk(256);
    dim3 blk512(512);
    dim3 blk1k(1024);

    // ---- CSR build (LDS-only atomics) + h0 concat fused into hist ----
    const long n4 = (long)N_NODES * DIM / 4;
    const int  nconcat = (int)((n4 + 511) / 512);
    prep_kernel<<<NB + nconcat, blk512, 0, stream>>>(erows, partial, n_edges,
                                                     uemb, iemb, temb, hA);
    scanB1_kernel<<<SB, blk, 0, stream>>>(partial, psum);
    scanB3_kernel<<<SB, blk, 0, stream>>>(partial, psum, offs);
    scatter1_kernel<<<NB, blk512, 0, stream>>>(erows, ecols, evals, offs, bkt_buf, n_edges);
    scatter2_kernel<<<NBUCKETS, blk1k, 0, stream>>>(bkt_buf, offs, row_span,
                                                    csr_cv, n_edges);

    // ---- layers 1,2: full-table SpMV (+fused batch gather of h_src);
    //      layer 3: batch rows only (+fused h2 gather via acc init) ----
    const int gwaves  = (2 * B + 3) / 4;
    const int fblocks = (int)(((long)(NWAVES + gwaves) * 64 + 255) / 256);
    spmv_csr_kernel<<<fblocks, blk, 0, stream>>>(row_span, csr_cv, hA, hB,
                                                 users, items, u_acc, it_acc, B, 1);
    spmv_csr_kernel<<<fblocks, blk, 0, stream>>>(row_span, csr_cv, hB, hA,
                                                 users, items, u_acc, it_acc, B, 0);
    const int bblocks = (int)(((long)gwaves * 64 + 255) / 256);
    spmv_batch_kernel<<<bblocks, blk, 0, stream>>>(row_span, csr_cv, hA,
                                                   users, items, u_acc, it_acc, B);

    dot_kernel<<<(B * 64 + 255) / 256, blk, 0, stream>>>(u_acc, it_acc, out, B);
}

// Round 12
// 502.026 us; speedup vs baseline: 1.7764x; 1.0360x over previous
//
#include <hip/hip_runtime.h>
#include <hip/hip_fp16.h>

#define N_USERS  200000
#define N_ITEMS  100000
#define N_TOPICS 100
#define N_NODES  (N_USERS + N_ITEMS + N_TOPICS)
#define DIM      64
#define BSHIFT   10                               // 1024 rows per bucket
#define BROWS    (1 << BSHIFT)
#define NBUCKETS ((N_NODES + BROWS - 1) >> BSHIFT)   // 294
#define NROWS_PAD (NBUCKETS * BROWS)              // 301,056
#define COLMASK  0x7FFFF                          // 19 bits (N_NODES < 2^19)
#define NB       512                              // binning blocks
#define NBSHIFT  9
#define M_TOT    (NBUCKETS * NB)                  // 150,528 partials
#define SB       256                              // scan blocks
#define CH       ((M_TOT + SB - 1) / SB)
// concat blocks in prep: ceil(N_NODES*DIM/4 / 512)
#define NCONCAT  (((N_NODES * DIM / 4) + 511) / 512)
// Padded-CSR: each row padded to a multiple of 8 edges (zero-val entries);
// each bucket owns a fixed region. Bucket padded total ~20650 +- ~140 (28
// sigma below 24576) -> no overflow for this dataset family.
#define BUCKET_CAP 24576

// Memory-system rules learned (r4/r6/r8/r9/r10):
//  - Scattered global ATOMICS write through L2 to the coherent point:
//    ~30-40 B fabric write per 4 B atomic, location-independent (r10:
//    NHCOPY=8 privatization changed WRITE_SIZE by exactly 0). Never on
//    hot paths; LDS atomics are fine.
//  - Scattered sub-line STORES amplify ~5-8x unless the destination
//    window's active lines fit per-XCD L2 AND one block (one XCD) owns
//    each window (r6: BSHIFT=10 cursor set; r8: S2SPLIT=8 cost 275 MB).

// ---------- prep: bucket hist [0,NB) + concat + batch acc init ----------

__global__ void prep_kernel(const int* __restrict__ rows,
                            int* __restrict__ partial, int n_edges,
                            const float* __restrict__ uemb,
                            const float* __restrict__ iemb,
                            const float* __restrict__ temb,
                            ushort* __restrict__ h0,
                            const int* __restrict__ users,
                            const int* __restrict__ items,
                            float* __restrict__ u_acc,
                            float* __restrict__ it_acc, int B) {
    __shared__ int h[NBUCKETS];
    if (blockIdx.x < NB) {
        for (int i = threadIdx.x; i < NBUCKETS; i += blockDim.x) h[i] = 0;
        __syncthreads();
        int stride = NB * blockDim.x;
        int gid0 = blockIdx.x * blockDim.x + threadIdx.x;
        int n4 = n_edges >> 2;
        const int4* r4 = (const int4*)rows;
        for (int e = gid0; e < n4; e += stride) {
            int4 v = r4[e];
            atomicAdd(&h[((unsigned)v.x) >> BSHIFT], 1);
            atomicAdd(&h[((unsigned)v.y) >> BSHIFT], 1);
            atomicAdd(&h[((unsigned)v.z) >> BSHIFT], 1);
            atomicAdd(&h[((unsigned)v.w) >> BSHIFT], 1);
        }
        for (int e = (n4 << 2) + gid0; e < n_edges; e += stride)
            atomicAdd(&h[((unsigned)rows[e]) >> BSHIFT], 1);
        __syncthreads();
        for (int i = threadIdx.x; i < NBUCKETS; i += blockDim.x)
            partial[blockIdx.x * NBUCKETS + i] = h[i];
    } else if (blockIdx.x < NB + NCONCAT) {
        int g = (blockIdx.x - NB) * blockDim.x + threadIdx.x;  // group of 4
        long base = (long)g * 4;
        if (base >= (long)N_NODES * DIM) return;
        const float* src;
        long off;
        if (base < (long)N_USERS * DIM)                 { src = uemb; off = base; }
        else if (base < (long)(N_USERS + N_ITEMS) * DIM){ src = iemb; off = base - (long)N_USERS * DIM; }
        else                                            { src = temb; off = base - (long)(N_USERS + N_ITEMS) * DIM; }
        float4 v = *(const float4*)(src + off);
        __half2 a = __floats2half2_rn(v.x, v.y);
        __half2 b = __floats2half2_rn(v.z, v.w);
        uint2 o;
        o.x = *(unsigned*)&a;
        o.y = *(unsigned*)&b;
        ((uint2*)h0)[g] = o;
    } else {
        // batch acc init: u_acc/it_acc = fp32 layer-0 embeddings (h0 term)
        int g = (blockIdx.x - NB - NCONCAT) * blockDim.x + threadIdx.x;
        int b    = g >> 4;
        int lane = g & 15;
        if (b >= B) return;
        int u  = users[b];
        int it = items[b];
        float4 uv = ((const float4*)(uemb + (size_t)u  * DIM))[lane];
        float4 iv = ((const float4*)(iemb + (size_t)it * DIM))[lane];
        ((float4*)(u_acc  + (size_t)b * DIM))[lane] = uv;
        ((float4*)(it_acc + (size_t)b * DIM))[lane] = iv;
    }
}

// Logical L = bucket*NB + block; physical = block*NBUCKETS + bucket.
__device__ __forceinline__ int phys_idx(int L) {
    return (L & (NB - 1)) * NBUCKETS + (L >> NBSHIFT);
}

__global__ void scanB1_kernel(const int* __restrict__ partial,
                              int* __restrict__ psum) {
    __shared__ int s[256];
    int tid = threadIdx.x;
    int c0 = blockIdx.x * CH;
    int c1 = min(M_TOT, c0 + CH);
    int sum = 0;
    for (int L = c0 + tid; L < c1; L += 256) sum += partial[phys_idx(L)];
    s[tid] = sum;
    __syncthreads();
    for (int off = 128; off > 0; off >>= 1) {
        if (tid < off) s[tid] += s[tid + off];
        __syncthreads();
    }
    if (tid == 0) psum[blockIdx.x] = s[0];
}

// scanB2 folded in: each block reduces psum[0..bid) itself (256 ints, cheap).
__global__ void scanB3_kernel(const int* __restrict__ partial,
                              const int* __restrict__ psum,
                              int* __restrict__ offs) {
    __shared__ int s[SB];
    __shared__ int tile[256];
    __shared__ int carry;
    int tid = threadIdx.x;
    s[tid] = (tid < blockIdx.x) ? psum[tid] : 0;
    __syncthreads();
    for (int off = 128; off > 0; off >>= 1) {
        if (tid < off) s[tid] += s[tid + off];
        __syncthreads();
    }
    if (tid == 0) carry = s[0];
    __syncthreads();
    int c0 = blockIdx.x * CH;
    int c1 = min(M_TOT, c0 + CH);
    for (int base = c0; base < c1; base += 256) {
        int L = base + tid;
        int v = (L < c1) ? partial[phys_idx(L)] : 0;
        tile[tid] = v;
        __syncthreads();
        for (int off = 1; off < 256; off <<= 1) {
            int t = (tid >= off) ? tile[tid - off] : 0;
            __syncthreads();
            tile[tid] += t;
            __syncthreads();
        }
        if (L < c1) offs[L] = carry + tile[tid] - v;
        __syncthreads();
        if (tid == 255) carry += tile[255];
        __syncthreads();
    }
}

// Bin edges into 1024-row buckets at exact positions; LDS-only atomics.
// 512 threads/block, grid NB; int4 edge loop MUST match prep hist mapping.
__global__ void scatter1_kernel(const int* __restrict__ rows,
                                const int* __restrict__ cols,
                                const float* __restrict__ vals,
                                const int* __restrict__ offs,
                                int2* __restrict__ bkt_buf, int n_edges) {
    __shared__ int lpos[NBUCKETS];
    for (int i = threadIdx.x; i < NBUCKETS; i += blockDim.x)
        lpos[i] = offs[i * NB + blockIdx.x];
    __syncthreads();
    int stride = NB * blockDim.x;
    int gid0 = blockIdx.x * blockDim.x + threadIdx.x;
    int n4 = n_edges >> 2;
    const int4*   r4 = (const int4*)rows;
    const int4*   c4 = (const int4*)cols;
    const float4* v4 = (const float4*)vals;
    for (int e = gid0; e < n4; e += stride) {
        int4 r = r4[e];
        int4 c = c4[e];
        float4 v = v4[e];
        #pragma unroll
        for (int j = 0; j < 4; ++j) {
            int rr = (j == 0) ? r.x : (j == 1) ? r.y : (j == 2) ? r.z : r.w;
            int cc = (j == 0) ? c.x : (j == 1) ? c.y : (j == 2) ? c.z : c.w;
            float vv = (j == 0) ? v.x : (j == 1) ? v.y : (j == 2) ? v.z : v.w;
            int b = ((unsigned)rr) >> BSHIFT;
            int pos = atomicAdd(&lpos[b], 1);
            int2 p;
            p.x = cc | ((rr & (BROWS - 1)) << 19);   // 19+10 bits < 32
            p.y = __float_as_int(vv);
            bkt_buf[pos] = p;
        }
    }
    for (int e = (n4 << 2) + gid0; e < n_edges; e += stride) {
        int rr = rows[e];
        int b = ((unsigned)rr) >> BSHIFT;
        int pos = atomicAdd(&lpos[b], 1);
        int2 p;
        p.x = cols[e] | ((rr & (BROWS - 1)) << 19);
        p.y = __float_as_int(vals[e]);
        bkt_buf[pos] = p;
    }
}

__device__ __forceinline__ int pad8(int x) { return (x + 7) & ~7; }

// One 1024-thread block per 1024-row bucket (one thread per row counter):
// LDS row hist from bkt_buf, pad8 scan (512 scan threads, 2 rows each),
// emit row_span, place edges into the bucket's fixed csr window (single
// block = single XCD per window), zero-fill pad slots (1 row/thread).
__global__ void scatter2_kernel(const int2* __restrict__ bkt_buf,
                                const int* __restrict__ offs,
                                int2* __restrict__ row_span,
                                int2* __restrict__ csr_cv, int n_edges) {
    __shared__ int lcnt[BROWS];
    __shared__ int lptr[BROWS];
    __shared__ int lfill[BROWS];
    __shared__ int s[512];
    int b = blockIdx.x;
    int t = threadIdx.x;
    int e0 = offs[b * NB];
    int e1 = (b == NBUCKETS - 1) ? n_edges : offs[(b + 1) * NB];
    lcnt[t]  = 0;
    lfill[t] = 0;
    __syncthreads();
    for (int e = e0 + t; e < e1; e += 1024)
        atomicAdd(&lcnt[((unsigned)bkt_buf[e].x) >> 19], 1);
    __syncthreads();
    if (t < 512) s[t] = pad8(lcnt[2 * t]) + pad8(lcnt[2 * t + 1]);
    __syncthreads();
    for (int off = 1; off < 512; off <<= 1) {
        int v = 0;
        if (t < 512 && t >= off) v = s[t - off];
        __syncthreads();
        if (t < 512) s[t] += v;          // inclusive over pairs
        __syncthreads();
    }
    if (t < 512) {
        int base = b * BUCKET_CAP + (t ? s[t - 1] : 0);
        int rbase = b << BSHIFT;
        int pe = pad8(lcnt[2 * t]);
        int po = pad8(lcnt[2 * t + 1]);
        int p_even = base;
        int p_odd  = base + pe;
        lptr[2 * t]     = p_even;
        lptr[2 * t + 1] = p_odd;
        int2 sp0; sp0.x = p_even; sp0.y = p_even + pe;
        int2 sp1; sp1.x = p_odd;  sp1.y = p_odd + po;
        row_span[rbase + 2 * t]     = sp0;   // rows >= N_NODES: len 0, harmless
        row_span[rbase + 2 * t + 1] = sp1;
    }
    __syncthreads();
    for (int e = e0 + t; e < e1; e += 1024) {
        int2 p = bkt_buf[e];
        int delta = ((unsigned)p.x) >> 19;
        int pos = lptr[delta] + atomicAdd(&lfill[delta], 1);
        int2 cv;
        cv.x = p.x & COLMASK;
        cv.y = p.y;
        csr_cv[pos] = cv;
    }
    __syncthreads();
    // zero-fill pad slots (col 0, val 0): one row per thread, <=7 each
    {
        int c  = lcnt[t];
        int cp = pad8(c);
        int p  = lptr[t];
        int2 z; z.x = 0; z.y = 0;
        for (int k = c; k < cp; ++k) csr_cv[p + k] = z;
    }
}

// ---------- SpMV helpers ----------
// fmaf(half2float(h), w, acc) lowers to v_fma_mix_f32 (fp16 src, fp32 MAC).
__device__ __forceinline__ float4 fma_mix4(const ushort* __restrict__ h,
                                           int row, int l16, float w,
                                           float4 acc) {
    uint2 r = ((const uint2*)(h + (size_t)row * DIM))[l16];
    __half2 h01 = *(__half2*)&r.x;
    __half2 h23 = *(__half2*)&r.y;
    acc.x = __builtin_fmaf(__half2float(__low2half(h01)),  w, acc.x);
    acc.y = __builtin_fmaf(__half2float(__high2half(h01)), w, acc.y);
    acc.z = __builtin_fmaf(__half2float(__low2half(h23)),  w, acc.z);
    acc.w = __builtin_fmaf(__half2float(__high2half(h23)), w, acc.w);
    return acc;
}

// Process one 8-edge batch: 4 unconditional int4 loads (rows are padded to
// a multiple of 8 with zero-val entries -> no clamps, no ternaries).
__device__ __forceinline__ float4 batch8(const int2* __restrict__ csr_cv,
                                         const ushort* __restrict__ h_src,
                                         int p, int l16, float4 acc) {
    const int4* q = (const int4*)(csr_cv + p);
    int4 a = q[0], b = q[1], c = q[2], d = q[3];
    acc = fma_mix4(h_src, a.x, l16, __int_as_float(a.y), acc);
    acc = fma_mix4(h_src, a.z, l16, __int_as_float(a.w), acc);
    acc = fma_mix4(h_src, b.x, l16, __int_as_float(b.y), acc);
    acc = fma_mix4(h_src, b.z, l16, __int_as_float(b.w), acc);
    acc = fma_mix4(h_src, c.x, l16, __int_as_float(c.y), acc);
    acc = fma_mix4(h_src, c.z, l16, __int_as_float(c.w), acc);
    acc = fma_mix4(h_src, d.x, l16, __int_as_float(d.y), acc);
    acc = fma_mix4(h_src, d.z, l16, __int_as_float(d.w), acc);
    return acc;
}

#define NWAVES ((N_NODES + 3) / 4)    // spmv waves; tail waves do the gather

// Full-table SpMV: 4 rows/wave (1 per 16-lane group), 8 edges in flight.
// (8-unroll is the proven optimum.) Tail waves (only when first >= 0)
// perform the fused batch-row gather of h_src into u_acc/it_acc.
__global__ void spmv_csr_kernel(const int2* __restrict__ row_span,
                                const int2* __restrict__ csr_cv,
                                const ushort* __restrict__ h_src,
                                ushort* __restrict__ h_dst,
                                const int* __restrict__ users,
                                const int* __restrict__ items,
                                float* __restrict__ u_acc,
                                float* __restrict__ it_acc,
                                int B, int first) {
    int wave = (int)(((long)blockIdx.x * blockDim.x + threadIdx.x) >> 6);
    int lane = threadIdx.x & 63;
    int g    = lane >> 4;
    int l16  = lane & 15;
    if (wave < NWAVES) {
        int r    = wave * 4 + g;
        int rc   = min(r, N_NODES - 1);
        int2 sp  = row_span[rc];
        int p0   = sp.x;
        int len  = (r < N_NODES) ? (sp.y - sp.x) : 0;   // multiple of 8
        int m = max(len, __shfl_xor(len, 16, 64));
        m = max(m, __shfl_xor(m, 32, 64));
        float4 acc = make_float4(0.f, 0.f, 0.f, 0.f);
        for (int off = 0; off < m; off += 8) {
            if (off < len)
                acc = batch8(csr_cv, h_src, p0 + off, l16, acc);
        }
        if (r < N_NODES) {
            __half2 a = __floats2half2_rn(acc.x, acc.y);
            __half2 b = __floats2half2_rn(acc.z, acc.w);
            uint2 o;
            o.x = *(unsigned*)&a;
            o.y = *(unsigned*)&b;
            ((uint2*)(h_dst + (size_t)r * DIM))[l16] = o;
        }
    } else {
        if (first < 0) return;           // spmv1: no tail work
        int s = (wave - NWAVES) * 4 + g;
        if (s >= 2 * B) return;
        int node = (s < B) ? users[s] : (N_USERS + items[s - B]);
        uint2 hr = ((const uint2*)(h_src + (size_t)node * DIM))[l16];
        float2 a01 = __half22float2(*(__half2*)&hr.x);
        float2 a23 = __half22float2(*(__half2*)&hr.y);
        float* dst = (s < B) ? (u_acc + (size_t)s * DIM)
                             : (it_acc + (size_t)(s - B) * DIM);
        float4* p = (float4*)dst + l16;
        float4 o = *p;
        o.x += a01.x; o.y += a01.y; o.z += a23.x; o.w += a23.y;
        *p = o;
    }
}

// Layer-3 SpMV over BATCH ROWS ONLY, with the final dot product FUSED.
// Wave handles batch pair b0=2w, b1=2w+1: groups {0,1} = (user,item) of b0,
// groups {2,3} = (user,item) of b1. acc = h2[node] (h2 term) + A.h2[node];
// then += stored u/it_acc (h0+h1 terms); partner exchange via shfl_xor 16
// computes dot(u_total, it_total) in-register; group-0/2 lane-0 writes out.
__global__ void spmv_batch_dot_kernel(const int2* __restrict__ row_span,
                                      const int2* __restrict__ csr_cv,
                                      const ushort* __restrict__ h_src,
                                      const int* __restrict__ users,
                                      const int* __restrict__ items,
                                      const float* __restrict__ u_acc,
                                      const float* __restrict__ it_acc,
                                      float* __restrict__ out, int B) {
    int wave = (int)(((long)blockIdx.x * blockDim.x + threadIdx.x) >> 6);
    int lane = threadIdx.x & 63;
    int g    = lane >> 4;
    int l16  = lane & 15;
    int b    = wave * 2 + (g >> 1);
    bool ok  = b < B;
    int node = 0;
    if (ok) node = ((g & 1) == 0) ? users[b] : (N_USERS + items[b]);
    float4 acc = make_float4(0.f, 0.f, 0.f, 0.f);
    if (ok) {
        uint2 hr = ((const uint2*)(h_src + (size_t)node * DIM))[l16];
        float2 a01 = __half22float2(*(__half2*)&hr.x);
        float2 a23 = __half22float2(*(__half2*)&hr.y);
        acc = make_float4(a01.x, a01.y, a23.x, a23.y);
    }
    int2 sp  = row_span[ok ? node : 0];
    int p0   = sp.x;
    int len  = ok ? (sp.y - sp.x) : 0;
    int m = max(len, __shfl_xor(len, 16, 64));
    m = max(m, __shfl_xor(m, 32, 64));
    for (int off = 0; off < m; off += 8) {
        if (off < len)
            acc = batch8(csr_cv, h_src, p0 + off, l16, acc);
    }
    if (ok) {
        const float* st = ((g & 1) == 0) ? (u_acc  + (size_t)b * DIM)
                                         : (it_acc + (size_t)b * DIM);
        float4 sv = ((const float4*)st)[l16];
        acc.x += sv.x; acc.y += sv.y; acc.z += sv.z; acc.w += sv.w;
    }
    // partner exchange: group g <-> g^1 (lane xor 16)
    float px = __shfl_xor(acc.x, 16, 64);
    float py = __shfl_xor(acc.y, 16, 64);
    float pz = __shfl_xor(acc.z, 16, 64);
    float pw = __shfl_xor(acc.w, 16, 64);
    float p = acc.x * px + acc.y * py + acc.z * pz + acc.w * pw;
    p += __shfl_down(p, 8, 16);
    p += __shfl_down(p, 4, 16);
    p += __shfl_down(p, 2, 16);
    p += __shfl_down(p, 1, 16);
    if (ok && (g & 1) == 0 && l16 == 0) out[b] = p * (1.0f / 16.0f);
}

extern "C" void kernel_launch(void* const* d_in, const int* in_sizes, int n_in,
                              void* d_out, int out_size, void* d_ws, size_t ws_size,
                              hipStream_t stream) {
    const int*   users = (const int*)d_in[0];
    const int*   items = (const int*)d_in[1];
    const int*   erows = (const int*)d_in[2];
    const int*   ecols = (const int*)d_in[3];
    const float* evals = (const float*)d_in[4];
    const float* uemb  = (const float*)d_in[5];
    const float* iemb  = (const float*)d_in[6];
    const float* temb  = (const float*)d_in[7];
    float* out = (float*)d_out;

    const int n_edges = in_sizes[2];
    const int B       = in_sizes[0];

    const size_t h2bytes = (((size_t)N_NODES * DIM * 2 + 255) / 256) * 256;  // 38.4 MB
    const size_t abytes  = (size_t)B * DIM * sizeof(float);                  // 4.2 MB
    const size_t spbytes = (((size_t)NROWS_PAD * 8 + 255) / 256) * 256;      // 2.4 MB
    const size_t csrbytes= (size_t)NBUCKETS * BUCKET_CAP * 8;                // 57.8 MB
    const size_t bkbytes = (size_t)n_edges * 8;                              // 40 MB
    const size_t mbytes  = (((size_t)M_TOT * 4 + 255) / 256) * 256;          // 0.6 MB

    char* ws = (char*)d_ws;
    size_t off = 0;
    ushort* hA       = (ushort*)(ws + off); off += h2bytes;
    ushort* hB       = (ushort*)(ws + off); off += h2bytes;
    float*  u_acc    = (float*) (ws + off); off += abytes;
    float*  it_acc   = (float*) (ws + off); off += abytes;
    int2*   row_span = (int2*)  (ws + off); off += spbytes;
    int2*   csr_cv   = (int2*)  (ws + off); off += csrbytes;
    int2*   bkt_buf  = (int2*)  (ws + off); off += bkbytes;
    int*    partial  = (int*)   (ws + off); off += mbytes;
    int*    offs     = (int*)   (ws + off); off += mbytes;
    int*    psum     = (int*)   (ws + off); off += 4096;   // ~189 MB total

    dim3 blk(256);
    dim3 blk512(512);
    dim3 blk1k(1024);

    // ---- CSR build (LDS-only atomics) + h0 concat + batch acc init ----
    const int ginit = (B * 16 + 511) / 512;
    prep_kernel<<<NB + NCONCAT + ginit, blk512, 0, stream>>>(
        erows, partial, n_edges, uemb, iemb, temb, hA,
        users, items, u_acc, it_acc, B);
    scanB1_kernel<<<SB, blk, 0, stream>>>(partial, psum);
    scanB3_kernel<<<SB, blk, 0, stream>>>(partial, psum, offs);
    scatter1_kernel<<<NB, blk512, 0, stream>>>(erows, ecols, evals, offs, bkt_buf, n_edges);
    scatter2_kernel<<<NBUCKETS, blk1k, 0, stream>>>(bkt_buf, offs, row_span,
                                                    csr_cv, n_edges);

    // ---- layer 1: full-table SpMV (no tail); layer 2: + h1 batch gather;
    //      layer 3: batch rows only + fused dot ----
    const int gwaves  = (2 * B + 3) / 4;
    const int blocks1 = (int)(((long)NWAVES * 64 + 255) / 256);
    const int blocks2 = (int)(((long)(NWAVES + gwaves) * 64 + 255) / 256);
    spmv_csr_kernel<<<blocks1, blk, 0, stream>>>(row_span, csr_cv, hA, hB,
                                                 users, items, u_acc, it_acc, B, -1);
    spmv_csr_kernel<<<blocks2, blk, 0, stream>>>(row_span, csr_cv, hB, hA,
                                                 users, items, u_acc, it_acc, B, 0);
    const int bwaves  = (B + 1) / 2;
    const int bblocks = (int)(((long)bwaves * 64 + 255) / 256);
    spmv_batch_dot_kernel<<<bblocks, blk, 0, stream>>>(row_span, csr_cv, hA,
                                                       users, items, u_acc, it_acc,
                                                       out, B);
}